// Round 5
// baseline (329.190 us; speedup 1.0000x reference)
//
#include <hip/hip_runtime.h>

#define BATCH 16
#define TFRAMES 2000
#define BINS 513
#define NFFT 1024
#define STEP 256
#define OUT_LEN 512768            // (TFRAMES-1)*STEP + NFFT
#define M_TOTAL (BATCH*TFRAMES)   // 32000

// ---- legacy packed layout (fallback atomic path) ----
#define KP 1024
#define PAIRS 512
#define JPACK 128

// ---- symmetry-split layout (fast path) ----
// C[n] = sum_p Ar[p]*cos(2pi p n/1024), Ar[0]=re0/1024 (B_cos[n][0]=1), Ar[p]=re[p]/512
// S[n] = sum_p Ai[p]*sin(2pi p n/1024), Ai[p]=-im[p]/512, slot 0 dead (B_sin[n][0]=0)
// x[n]      = C[n]+S[n]+t,  x[1024-n] = C[n]-S[n]+t,  t=(-1)^n*re512/1024, n=0..511
// x[512]    = sum_k (-1)^k Ar[k] + re512/1024   (fused into pack wave-reduce)
// OLA fused into the GEMM epilogue: out[b][t*256+n] += x[n]*win[n] (atomicAdd,
// exactly 4 contributions per out sample, spread across different blocks).
#define KP2 512

typedef _Float16 f16x8 __attribute__((ext_vector_type(8)));
typedef float    f32x4 __attribute__((ext_vector_type(4)));

__device__ __forceinline__ void async_copy16(const void* g, void* l) {
    __builtin_amdgcn_global_load_lds(
        (const __attribute__((address_space(1))) unsigned*)g,
        (__attribute__((address_space(3))) unsigned*)l, 16, 0, 0);
}

// ---------------- fused fast-path pack kernel (A + B in one launch) ---------
#define PACKA_BLOCKS ((M_TOTAL * 64) / 256)   // 8000
#define PACKB_BLOCKS ((512 * 64) / 256)       // 128

__global__ __launch_bounds__(256) void pack_AB(const float* __restrict__ sre,
                                               const float* __restrict__ sim,
                                               const float* __restrict__ dcos,
                                               const float* __restrict__ dsin,
                                               const float* __restrict__ window,
                                               uint4* __restrict__ Ar,
                                               uint4* __restrict__ Ai,
                                               float* __restrict__ re512f,
                                               float* __restrict__ out,
                                               uint4* __restrict__ Bc,
                                               uint4* __restrict__ Bs)
{
    if (blockIdx.x < PACKA_BLOCKS) {
        // ---- A part: one wave per row m; thread j handles k = 8j..8j+7 ----
        const int idx = blockIdx.x * 256 + threadIdx.x;   // m*64 + j
        const int m = idx >> 6;
        const int j = idx & 63;
        const int k0 = j * 8;
        const size_t base = (size_t)m * BINS + k0;
        float ar[8], ai[8];
        #pragma unroll
        for (int i = 0; i < 8; i++) {
            ar[i] =  sre[base + i] * (1.0f/512.0f);
            ai[i] = -sim[base + i] * (1.0f/512.0f);
        }
        float r5 = 0.0f;
        if (j == 0) {
            ar[0] = sre[(size_t)m * BINS] * (1.0f/1024.0f);   // DC, B_cos[n][0]=1
            ai[0] = 0.0f;                                      // dead, B_sin[n][0]=0
            r5 = sre[(size_t)m * BINS + 512] * (1.0f/1024.0f);
            re512f[m] = r5;
        }
        union { _Float16 h[8]; uint4 u; } pr, pi;
        #pragma unroll
        for (int i = 0; i < 8; i++) { pr.h[i] = (_Float16)ar[i]; pi.h[i] = (_Float16)ai[i]; }
        Ar[idx] = pr.u;
        Ai[idx] = pi.u;

        // fused n=512 column: x[512] = sum_k (-1)^k Ar[k] + re512/1024
        float s = ar[0]-ar[1]+ar[2]-ar[3]+ar[4]-ar[5]+ar[6]-ar[7];
        #pragma unroll
        for (int off = 32; off > 0; off >>= 1) s += __shfl_xor(s, off);
        if (j == 0) {
            const int b = m / TFRAMES;
            const int t = m - b * TFRAMES;
            atomicAdd(&out[(size_t)b * OUT_LEN + (size_t)t * STEP + 512],
                      (s + r5) * window[512]);
        }
    } else {
        // ---- B part ----
        const int idx = (blockIdx.x - PACKA_BLOCKS) * 256 + threadIdx.x;  // n*64 + j
        const int n = idx >> 6;
        const int j = idx & 63;
        const int k0 = j * 8;
        const size_t base = (size_t)n * NFFT + k0;
        union { _Float16 h[8]; uint4 u; } pc, ps;
        #pragma unroll
        for (int i = 0; i < 8; i++) {
            pc.h[i] = (_Float16)dcos[base + i];
            ps.h[i] = (_Float16)dsin[base + i];
        }
        if (j == 0) { pc.h[0] = (_Float16)1.0f; ps.h[0] = (_Float16)0.0f; }
        Bc[idx] = pc.u;
        Bs[idx] = ps.u;
    }
}

// ---------------- dual symmetry GEMM, BK=64, 8 K-steps (R3-verified loop) ---
// Block: 128(M) x 64(N of half-domain), 2x2 waves, dual 64x32 per wave.
// LDS: four PLANAR tiles with 128B rows (8 x 16B chunks), proven 8-slot
// swizzle slot = chunk^(row&7) per plane, applied on the per-lane GLOBAL
// source; LDS dest lane-linear (global_load_lds rule). Measured 0 conflicts.
// Epilogue: fused overlap-add via atomicAdd into out (replaces frames+gather).
#define BM3 128
#define BN3 64
#define BK3 64    // halves per matrix per step -> 8 steps over KP2=512

__global__ __launch_bounds__(256, 3) void gemm_dual(
    const _Float16* __restrict__ Ar, const _Float16* __restrict__ Ai,
    const _Float16* __restrict__ Bc, const _Float16* __restrict__ Bs,
    const float* __restrict__ re512f, const float* __restrict__ window,
    float* __restrict__ out)
{
    __shared__ _Float16 LAr[BM3 * BK3];   // 16 KB
    __shared__ _Float16 LAi[BM3 * BK3];   // 16 KB
    __shared__ _Float16 LBc[BN3 * BK3];   //  8 KB
    __shared__ _Float16 LBs[BN3 * BK3];   //  8 KB

    const int raw = blockIdx.x;                    // 0..1999
    const int idx = (raw & 7) * 250 + (raw >> 3);  // XCD-grouping bijection
    const int mt = idx >> 3;                       // 0..249
    const int nt = idx & 7;                        // 0..7
    const int m0 = mt * BM3;
    const int n0 = nt * BN3;

    const int tid  = threadIdx.x;
    const int w    = tid >> 6;         // wave 0..3
    const int lane = tid & 63;
    const int wm   = w & 1;            // M-half (64 rows)
    const int wn   = w >> 1;           // N-half (32 cols)
    const int row16 = lane & 15;
    const int quad  = lane >> 4;

    // staging: srow 0..7, swizzled chunk slot (applied to global source)
    const int srow  = lane >> 3;
    const int sslot = (lane & 7) ^ srow;
    const _Float16* gAr = Ar + (size_t)(m0 + w*32 + srow) * KP2 + sslot * 8;
    const _Float16* gAi = Ai + (size_t)(m0 + w*32 + srow) * KP2 + sslot * 8;
    const _Float16* gBc = Bc + (size_t)(n0 + w*16 + srow) * KP2 + sslot * 8;
    const _Float16* gBs = Bs + (size_t)(n0 + w*16 + srow) * KP2 + sslot * 8;

    f32x4 aC[4][2] = {};
    f32x4 aS[4][2] = {};

    for (int k0 = 0; k0 < KP2; k0 += BK3) {        // 8 steps
        #pragma unroll
        for (int t = 0; t < 4; t++) {
            async_copy16(gAr + (size_t)t*8*KP2 + k0, LAr + (w*32 + t*8) * BK3);
            async_copy16(gAi + (size_t)t*8*KP2 + k0, LAi + (w*32 + t*8) * BK3);
        }
        #pragma unroll
        for (int t = 0; t < 2; t++) {
            async_copy16(gBc + (size_t)t*8*KP2 + k0, LBc + (w*16 + t*8) * BK3);
            async_copy16(gBs + (size_t)t*8*KP2 + k0, LBs + (w*16 + t*8) * BK3);
        }
        __syncthreads();               // drain staging

        #pragma unroll
        for (int ks = 0; ks < 2; ks++) {
            f16x8 ar[4], ai_[4], bc[2], bs_[2];
            #pragma unroll
            for (int i = 0; i < 4; i++) {
                const int rA = wm*64 + i*16 + row16;
                const int sl = ((ks*4 + quad) ^ (rA & 7)) * 8;
                ar[i]  = *(const f16x8*)&LAr[rA * BK3 + sl];
                ai_[i] = *(const f16x8*)&LAi[rA * BK3 + sl];
            }
            #pragma unroll
            for (int j = 0; j < 2; j++) {
                const int rB = wn*32 + j*16 + row16;
                const int sl = ((ks*4 + quad) ^ (rB & 7)) * 8;
                bc[j]  = *(const f16x8*)&LBc[rB * BK3 + sl];
                bs_[j] = *(const f16x8*)&LBs[rB * BK3 + sl];
            }
            #pragma unroll
            for (int i = 0; i < 4; i++)
                #pragma unroll
                for (int j = 0; j < 2; j++) {
                    aC[i][j] = __builtin_amdgcn_mfma_f32_16x16x32_f16(ar[i],  bc[j],  aC[i][j], 0, 0, 0);
                    aS[i][j] = __builtin_amdgcn_mfma_f32_16x16x32_f16(ai_[i], bs_[j], aS[i][j], 0, 0, 0);
                }
        }
        __syncthreads();               // all reads retired before overwrite
    }

    // Fused OLA epilogue. C/D layout: col = lane&15 (-> n), row = quad*4 + reg.
    // x[n] = C+S+t5 (win[n]); x[1024-n] = C-S+t5 (win[1024-n]), t5 = (-1)^n re512/1024.
    // out[b][t*256 + n] += x[n]*win[n]  (each out sample: exactly 4 adds, from
    // 4 different nt-blocks -> low atomic contention).
    #pragma unroll
    for (int j = 0; j < 2; j++) {
        const int n = n0 + wn*32 + j*16 + row16;           // 0..511
        const float wpos = window[n];
        const float wneg = window[(NFFT - n) & (NFFT - 1)]; // n=0 unused
        #pragma unroll
        for (int i = 0; i < 4; i++) {
            const int mrow = m0 + wm*64 + i*16 + quad*4;
            const float4 r5v = *(const float4*)&re512f[mrow];
            const float r5a[4] = {r5v.x, r5v.y, r5v.z, r5v.w};
            const f32x4 c = aC[i][j];
            const f32x4 s = aS[i][j];
            #pragma unroll
            for (int r = 0; r < 4; r++) {
                const float t5 = (n & 1) ? -r5a[r] : r5a[r];
                const int m = mrow + r;
                const int b = m / TFRAMES;
                const int t = m - b * TFRAMES;
                float* obase = out + (size_t)b * OUT_LEN + (size_t)t * STEP;
                atomicAdd(&obase[n], (c[r] + s[r] + t5) * wpos);
                if (n) atomicAdd(&obase[NFFT - n], (c[r] - s[r] + t5) * wneg);
            }
        }
    }
}

// ---------------- legacy pack kernels (fallback atomic path) ----------------
__global__ __launch_bounds__(256) void pack_A(const float* __restrict__ sre,
                                              const float* __restrict__ sim,
                                              uint4* __restrict__ Au)
{
    const int idx = blockIdx.x * 256 + threadIdx.x;
    const int m = idx >> 7;
    const int j = idx & 127;
    const int k0 = j * 4;
    const size_t base = (size_t)m * BINS + k0;
    union { _Float16 h[8]; uint4 u; } pk;
    if (j == 0) {
        const float re0   = sre[(size_t)m * BINS];
        const float re512 = sre[(size_t)m * BINS + 512];
        pk.h[0] = (_Float16)(re0   * (1.0f/1024.0f));
        pk.h[1] = (_Float16)(re512 * (1.0f/1024.0f));
        #pragma unroll
        for (int i = 1; i < 4; i++) {
            pk.h[2*i]   = (_Float16)( sre[base + i] * (1.0f/512.0f));
            pk.h[2*i+1] = (_Float16)(-sim[base + i] * (1.0f/512.0f));
        }
    } else {
        #pragma unroll
        for (int i = 0; i < 4; i++) {
            pk.h[2*i]   = (_Float16)( sre[base + i] * (1.0f/512.0f));
            pk.h[2*i+1] = (_Float16)(-sim[base + i] * (1.0f/512.0f));
        }
    }
    Au[idx] = pk.u;
}

__global__ __launch_bounds__(256) void pack_B(const float* __restrict__ dcos,
                                              const float* __restrict__ dsin,
                                              unsigned* __restrict__ Bu)
{
    const int idx = blockIdx.x * 256 + threadIdx.x;
    const int n = idx >> 9;
    const int p = idx & 511;
    float b0, b1;
    if (p == 0) {
        b0 = 1.0f;
        b1 = (n & 1) ? -1.0f : 1.0f;
    } else {
        const size_t base = (size_t)n * NFFT + p;
        b0 = dcos[base];
        b1 = dsin[base];
    }
    union { _Float16 h[2]; unsigned u; } pk;
    pk.h[0] = (_Float16)b0;
    pk.h[1] = (_Float16)b1;
    Bu[idx] = pk.u;
}

// ---------------- legacy 128x128 MFMA GEMM (atomic fallback) ----------------
#define BM 128
#define BN 128
#define BK 64

__global__ __launch_bounds__(256, 3) void gemm_f16_atomic(const _Float16* __restrict__ A,
                                                          const _Float16* __restrict__ B,
                                                          const float* __restrict__ window,
                                                          float* __restrict__ out)
{
    __shared__ _Float16 As[BM * BK];
    __shared__ _Float16 Bs[BN * BK];

    const int raw = blockIdx.x;
    const int idx = (raw & 7) * 250 + (raw >> 3);
    const int mt = idx >> 3;
    const int nt = idx & 7;
    const int m0 = mt * BM;
    const int n0 = nt * BN;

    const int tid  = threadIdx.x;
    const int w    = tid >> 6;
    const int lane = tid & 63;
    const int wm   = w & 1;
    const int wn   = w >> 1;
    const int row16 = lane & 15;
    const int quad  = lane >> 4;

    const int srow   = lane >> 3;
    const int schunk = (lane & 7) ^ srow;
    const _Float16* gA = A + (size_t)(m0 + w*32 + srow) * KP + schunk * 8;
    const _Float16* gB = B + (size_t)(n0 + w*32 + srow) * KP + schunk * 8;

    f32x4 acc[4][4] = {};

    for (int k0 = 0; k0 < KP; k0 += BK) {
        #pragma unroll
        for (int t = 0; t < 4; t++) {
            async_copy16(gA + (size_t)t*8*KP + k0, As + (w*4 + t) * 512);
            async_copy16(gB + (size_t)t*8*KP + k0, Bs + (w*4 + t) * 512);
        }
        __syncthreads();
        #pragma unroll
        for (int c = 0; c < 2; c++) {
            f16x8 af[4], bf[4];
            #pragma unroll
            for (int i = 0; i < 4; i++) {
                const int rowA = wm*64 + i*16 + row16;
                const int chA  = (c*4 + quad) ^ (row16 & 7);
                af[i] = *(const f16x8*)&As[rowA * BK + chA * 8];
            }
            #pragma unroll
            for (int j = 0; j < 4; j++) {
                const int rowB = wn*64 + j*16 + row16;
                const int chB  = (c*4 + quad) ^ (row16 & 7);
                bf[j] = *(const f16x8*)&Bs[rowB * BK + chB * 8];
            }
            #pragma unroll
            for (int i = 0; i < 4; i++)
                #pragma unroll
                for (int j = 0; j < 4; j++)
                    acc[i][j] = __builtin_amdgcn_mfma_f32_16x16x32_f16(af[i], bf[j], acc[i][j], 0, 0, 0);
        }
        __syncthreads();
    }

    #pragma unroll
    for (int j = 0; j < 4; j++) {
        const int n = n0 + wn*64 + j*16 + row16;
        const float win = window[n];
        #pragma unroll
        for (int i = 0; i < 4; i++) {
            const int mrow = m0 + wm*64 + i*16 + quad*4;
            const f32x4 c = acc[i][j];
            #pragma unroll
            for (int r = 0; r < 4; r++) {
                const int m = mrow + r;
                const int b = m / TFRAMES;
                const int t = m - b * TFRAMES;
                atomicAdd(&out[(size_t)b * OUT_LEN + (size_t)t * STEP + n], c[r] * win);
            }
        }
    }
}

// ---------------- round-1 fp32 fallback (known-correct) ----------------
#define MT 64
#define NT 64
#define KT 16
#define PAD 4
__global__ __launch_bounds__(256) void istft_gemm_ola_f32(
    const float* __restrict__ sre, const float* __restrict__ sim,
    const float* __restrict__ dcos, const float* __restrict__ dsin,
    const float* __restrict__ window, float* __restrict__ out)
{
    __shared__ float As_re[KT][MT + PAD];
    __shared__ float As_im[KT][MT + PAD];
    __shared__ float Bs_c[KT][NT + PAD];
    __shared__ float Bs_s[KT][NT + PAD];
    const int ntile = blockIdx.x & 15;
    const int mtile = blockIdx.x >> 4;
    const int m0 = mtile * MT, n0 = ntile * NT;
    const int tid = threadIdx.x;
    const int tx = tid & 15, ty = tid >> 4;
    const int lcol = tid & 15, lrow = tid >> 4;
    float acc[4][4] = {};
    for (int k0 = 0; k0 < BINS; k0 += KT) {
        const int k = k0 + lcol;
        const bool kvalid = (k < BINS);
        const float w = kvalid ? ((k == 0 || k == 512) ? (1.0f/1024.0f) : (2.0f/1024.0f)) : 0.0f;
        #pragma unroll
        for (int i = 0; i < 4; i++) {
            const int m = m0 + lrow + i*16;
            const size_t base = (size_t)m * BINS + k;
            As_re[lcol][lrow + i*16] = kvalid ?  w * sre[base] : 0.0f;
            As_im[lcol][lrow + i*16] = kvalid ? -w * sim[base] : 0.0f;
        }
        #pragma unroll
        for (int i = 0; i < 4; i++) {
            const int n = n0 + lrow + i*16;
            const size_t base = (size_t)n * NFFT + k;
            Bs_c[lcol][lrow + i*16] = kvalid ? dcos[base] : 0.0f;
            Bs_s[lcol][lrow + i*16] = kvalid ? dsin[base] : 0.0f;
        }
        __syncthreads();
        #pragma unroll
        for (int kk = 0; kk < KT; kk++) {
            const float4 ar = *(const float4*)&As_re[kk][ty*4];
            const float4 ai = *(const float4*)&As_im[kk][ty*4];
            const float4 bc = *(const float4*)&Bs_c[kk][tx*4];
            const float4 bs = *(const float4*)&Bs_s[kk][tx*4];
            const float a_r[4] = {ar.x, ar.y, ar.z, ar.w};
            const float a_i[4] = {ai.x, ai.y, ai.z, ai.w};
            const float b_c[4] = {bc.x, bc.y, bc.z, bc.w};
            const float b_s[4] = {bs.x, bs.y, bs.z, bs.w};
            #pragma unroll
            for (int i = 0; i < 4; i++)
                #pragma unroll
                for (int j = 0; j < 4; j++)
                    acc[i][j] += a_r[i]*b_c[j] + a_i[i]*b_s[j];
        }
        __syncthreads();
    }
    #pragma unroll
    for (int i = 0; i < 4; i++) {
        const int m = m0 + ty*4 + i;
        const int b = m / TFRAMES;
        const int t = m - b * TFRAMES;
        const size_t obase = (size_t)b * OUT_LEN + (size_t)t * STEP;
        #pragma unroll
        for (int j = 0; j < 4; j++) {
            const int n = n0 + tx*4 + j;
            atomicAdd(&out[obase + n], acc[i][j] * window[n]);
        }
    }
}

// ---------------- launch ----------------
extern "C" void kernel_launch(void* const* d_in, const int* in_sizes, int n_in,
                              void* d_out, int out_size, void* d_ws, size_t ws_size,
                              hipStream_t stream) {
    const float* sre    = (const float*)d_in[0];
    const float* sim    = (const float*)d_in[1];
    const float* dcos   = (const float*)d_in[2];
    const float* dsin   = (const float*)d_in[3];
    const float* window = (const float*)d_in[4];
    float* out = (float*)d_out;

    // fast-path workspace layout (no frames buffer needed anymore)
    const size_t WS_AR = (size_t)M_TOTAL * KP2 * sizeof(_Float16);    // 32,768,000
    const size_t WS_AI = WS_AR;
    const size_t WS_R5 = (size_t)M_TOTAL * sizeof(float);             //    128,000
    const size_t WS_BC = (size_t)512 * KP2 * sizeof(_Float16);        //    524,288
    const size_t WS_BS = WS_BC;
    const size_t NEED  = WS_AR + WS_AI + WS_R5 + WS_BC + WS_BS;

    // legacy atomic-path workspace
    const size_t WS_A = (size_t)M_TOTAL * KP * sizeof(_Float16);
    const size_t WS_B = (size_t)NFFT    * KP * sizeof(_Float16);

    if (ws_size >= NEED) {
        char* p = (char*)d_ws;
        _Float16* Ar = (_Float16*)p;  p += WS_AR;
        _Float16* Ai = (_Float16*)p;  p += WS_AI;
        float*    r5 = (float*)p;     p += WS_R5;
        _Float16* Bc = (_Float16*)p;  p += WS_BC;
        _Float16* Bs = (_Float16*)p;

        hipMemsetAsync(out, 0, (size_t)out_size * sizeof(float), stream);

        pack_AB<<<PACKA_BLOCKS + PACKB_BLOCKS, 256, 0, stream>>>(
            sre, sim, dcos, dsin, window,
            (uint4*)Ar, (uint4*)Ai, r5, out, (uint4*)Bc, (uint4*)Bs);

        const int grid = (M_TOTAL / BM3) * (KP2 / BN3);   // 250 * 8 = 2000
        gemm_dual<<<grid, 256, 0, stream>>>(Ar, Ai, Bc, Bs, r5, window, out);
    } else if (ws_size >= WS_A + WS_B) {
        hipMemsetAsync(out, 0, (size_t)out_size * sizeof(float), stream);
        _Float16* Apk = (_Float16*)d_ws;
        _Float16* Bpk = (_Float16*)((char*)d_ws + WS_A);
        pack_A<<<(M_TOTAL * JPACK) / 256, 256, 0, stream>>>(sre, sim, (uint4*)Apk);
        pack_B<<<(NFFT * PAIRS) / 256, 256, 0, stream>>>(dcos, dsin, (unsigned*)Bpk);
        const int grid = (M_TOTAL / BM) * (NFFT / BN);
        gemm_f16_atomic<<<grid, 256, 0, stream>>>(Apk, Bpk, window, out);
    } else {
        hipMemsetAsync(out, 0, (size_t)out_size * sizeof(float), stream);
        const int grid = (M_TOTAL / MT) * (NFFT / NT);
        istft_gemm_ola_f32<<<grid, 256, 0, stream>>>(sre, sim, dcos, dsin, window, out);
    }
}

// Round 6
// 256.978 us; speedup vs baseline: 1.2810x; 1.2810x over previous
//
#include <hip/hip_runtime.h>

#define BATCH 16
#define TFRAMES 2000
#define BINS 513
#define NFFT 1024
#define STEP 256
#define OUT_LEN 512768            // (TFRAMES-1)*STEP + NFFT
#define M_TOTAL (BATCH*TFRAMES)   // 32000

// ---- legacy packed layout (fallback atomic path) ----
#define KP 1024
#define PAIRS 512
#define JPACK 128

// ---- symmetry-split layout (fast path) ----
// C[n] = sum_p Ar[p]*cos(2pi p n/1024), Ar[0]=re0/1024 (B_cos[n][0]=1), Ar[p]=re[p]/512
// S[n] = sum_p Ai[p]*sin(2pi p n/1024), Ai[p]=-im[p]/512, slot 0 dead (B_sin[n][0]=0)
// x[n]      = C[n]+S[n]+t,  x[1024-n] = C[n]-S[n]+t,  t=(-1)^n*re512/1024, n=0..511
// x[512]    = sum_k (-1)^k Ar[k] + re512/1024   (fused into pack wave-reduce)
#define KP2 512

typedef _Float16 f16x8 __attribute__((ext_vector_type(8)));
typedef float    f32x4 __attribute__((ext_vector_type(4)));

__device__ __forceinline__ void async_copy16(const void* g, void* l) {
    __builtin_amdgcn_global_load_lds(
        (const __attribute__((address_space(1))) unsigned*)g,
        (__attribute__((address_space(3))) unsigned*)l, 16, 0, 0);
}

// ---------------- fused fast-path pack kernel (A + B in one launch) ---------
#define PACKA_BLOCKS ((M_TOTAL * 64) / 256)   // 8000
#define PACKB_BLOCKS ((512 * 64) / 256)       // 128

__global__ __launch_bounds__(256) void pack_AB(const float* __restrict__ sre,
                                               const float* __restrict__ sim,
                                               const float* __restrict__ dcos,
                                               const float* __restrict__ dsin,
                                               const float* __restrict__ window,
                                               uint4* __restrict__ Ar,
                                               uint4* __restrict__ Ai,
                                               float* __restrict__ re512f,
                                               _Float16* __restrict__ frames,
                                               uint4* __restrict__ Bc,
                                               uint4* __restrict__ Bs)
{
    if (blockIdx.x < PACKA_BLOCKS) {
        // ---- A part: one wave per row m; thread j handles k = 8j..8j+7 ----
        const int idx = blockIdx.x * 256 + threadIdx.x;   // m*64 + j
        const int m = idx >> 6;
        const int j = idx & 63;
        const int k0 = j * 8;
        const size_t base = (size_t)m * BINS + k0;
        float ar[8], ai[8];
        #pragma unroll
        for (int i = 0; i < 8; i++) {
            ar[i] =  sre[base + i] * (1.0f/512.0f);
            ai[i] = -sim[base + i] * (1.0f/512.0f);
        }
        float r5 = 0.0f;
        if (j == 0) {
            ar[0] = sre[(size_t)m * BINS] * (1.0f/1024.0f);   // DC, B_cos[n][0]=1
            ai[0] = 0.0f;                                      // dead, B_sin[n][0]=0
            r5 = sre[(size_t)m * BINS + 512] * (1.0f/1024.0f);
            re512f[m] = r5;
        }
        union { _Float16 h[8]; uint4 u; } pr, pi;
        #pragma unroll
        for (int i = 0; i < 8; i++) { pr.h[i] = (_Float16)ar[i]; pi.h[i] = (_Float16)ai[i]; }
        Ar[idx] = pr.u;
        Ai[idx] = pi.u;

        // fused n=512 column: x[512] = sum_k (-1)^k Ar[k] + re512/1024
        float s = ar[0]-ar[1]+ar[2]-ar[3]+ar[4]-ar[5]+ar[6]-ar[7];
        #pragma unroll
        for (int off = 32; off > 0; off >>= 1) s += __shfl_xor(s, off);
        if (j == 0)
            frames[(size_t)m * NFFT + 512] = (_Float16)((s + r5) * window[512]);
    } else {
        // ---- B part ----
        const int idx = (blockIdx.x - PACKA_BLOCKS) * 256 + threadIdx.x;  // n*64 + j
        const int n = idx >> 6;
        const int j = idx & 63;
        const int k0 = j * 8;
        const size_t base = (size_t)n * NFFT + k0;
        union { _Float16 h[8]; uint4 u; } pc, ps;
        #pragma unroll
        for (int i = 0; i < 8; i++) {
            pc.h[i] = (_Float16)dcos[base + i];
            ps.h[i] = (_Float16)dsin[base + i];
        }
        if (j == 0) { pc.h[0] = (_Float16)1.0f; ps.h[0] = (_Float16)0.0f; }
        Bc[idx] = pc.u;
        Bs[idx] = ps.u;
    }
}

// ---------------- dual symmetry GEMM, BK=32, dbuf + COUNTED vmcnt (T3/T4) ---
// Block: 128(M) x 64(N of half-domain), 2x2 waves, dual 64x32 per wave.
// LDS: 2 buffers x {LAr 8K, LAi 8K, LBc 4K, LBs 4K} = 48 KB total -> 3 blk/CU.
// Rows are 64 B = 4 x 16B chunks; swizzle slot = chunk^(row&3), applied on the
// per-lane GLOBAL source (dest lane-linear, global_load_lds rule).
// Pipeline per tile kt: ds_read frags(kt) -> lgkmcnt(0) -> s_barrier ->
//   STAGE(kt+2 -> same buf) -> 16 MFMA -> s_waitcnt vmcnt(6) (tile kt+1
//   landed, kt+2 still IN FLIGHT across the barrier) -> s_barrier.
// This is the counted-vmcnt fix for R4's drain-everything __syncthreads.
#define BM3 128
#define BN3 64
#define BK3 32
#define NSTEP (KP2 / BK3)   // 16

__global__ __launch_bounds__(256, 3) void gemm_dual(
    const _Float16* __restrict__ Ar, const _Float16* __restrict__ Ai,
    const _Float16* __restrict__ Bc, const _Float16* __restrict__ Bs,
    const float* __restrict__ re512f, const float* __restrict__ window,
    _Float16* __restrict__ frames)
{
    __shared__ _Float16 LAr[2][BM3 * BK3];   // 2 x 8 KB
    __shared__ _Float16 LAi[2][BM3 * BK3];   // 2 x 8 KB
    __shared__ _Float16 LBc[2][BN3 * BK3];   // 2 x 4 KB
    __shared__ _Float16 LBs[2][BN3 * BK3];   // 2 x 4 KB

    const int raw = blockIdx.x;                    // 0..1999
    const int idx = (raw & 7) * 250 + (raw >> 3);  // XCD-grouping bijection
    const int mt = idx >> 3;                       // 0..249
    const int nt = idx & 7;                        // 0..7
    const int m0 = mt * BM3;
    const int n0 = nt * BN3;

    const int tid  = threadIdx.x;
    const int w    = tid >> 6;         // wave 0..3
    const int lane = tid & 63;
    const int wm   = w & 1;            // M-half (64 rows)
    const int wn   = w >> 1;           // N-half (32 cols)
    const int row16 = lane & 15;
    const int quad  = lane >> 4;

    // staging: each async_copy16 writes 1 KB = 16 rows x 4 chunks, lane-linear.
    // lane -> dest (row srow, chunk lane&3); source fetches logical chunk
    // (lane&3)^(srow&3) so that READ at slot quad^(row&3) retrieves chunk quad.
    const int srow   = lane >> 2;                 // 0..15
    const int schunk = (lane & 3) ^ (srow & 3);   // inverse-swizzled source chunk
    const _Float16* gAr = Ar + (size_t)(m0 + w*32 + srow) * KP2 + schunk * 8;
    const _Float16* gAi = Ai + (size_t)(m0 + w*32 + srow) * KP2 + schunk * 8;
    const _Float16* gBc = Bc + (size_t)(n0 + w*16 + srow) * KP2 + schunk * 8;
    const _Float16* gBs = Bs + (size_t)(n0 + w*16 + srow) * KP2 + schunk * 8;

    // 6 async copies per thread per tile (FIFO order fixed for vmcnt counting)
    #define STAGE(tk, bf) do { \
        const size_t kk = (size_t)(tk) * BK3; \
        async_copy16(gAr + kk,                    &LAr[bf][(w*32     ) * BK3]); \
        async_copy16(gAr + (size_t)16*KP2 + kk,   &LAr[bf][(w*32 + 16) * BK3]); \
        async_copy16(gAi + kk,                    &LAi[bf][(w*32     ) * BK3]); \
        async_copy16(gAi + (size_t)16*KP2 + kk,   &LAi[bf][(w*32 + 16) * BK3]); \
        async_copy16(gBc + kk,                    &LBc[bf][(w*16     ) * BK3]); \
        async_copy16(gBs + kk,                    &LBs[bf][(w*16     ) * BK3]); \
    } while (0)

    f32x4 aC[4][2] = {};
    f32x4 aS[4][2] = {};

    // prologue: stage tiles 0 and 1; wait tile 0 only (tile 1 stays in flight)
    STAGE(0, 0);
    STAGE(1, 1);
    asm volatile("s_waitcnt vmcnt(6)" ::: "memory");
    __builtin_amdgcn_sched_barrier(0);
    __builtin_amdgcn_s_barrier();

    #pragma unroll 2
    for (int kt = 0; kt < NSTEP; ++kt) {
        const int bf = kt & 1;

        // ---- fragment reads from buf bf ----
        f16x8 ar[4], ai_[4], bc[2], bs_[2];
        #pragma unroll
        for (int i = 0; i < 4; i++) {
            const int rA = wm*64 + i*16 + row16;
            const int sl = (quad ^ (rA & 3)) * 8;
            ar[i]  = *(const f16x8*)&LAr[bf][rA * BK3 + sl];
            ai_[i] = *(const f16x8*)&LAi[bf][rA * BK3 + sl];
        }
        #pragma unroll
        for (int j = 0; j < 2; j++) {
            const int rB = wn*32 + j*16 + row16;
            const int sl = (quad ^ (rB & 3)) * 8;
            bc[j]  = *(const f16x8*)&LBc[bf][rB * BK3 + sl];
            bs_[j] = *(const f16x8*)&LBs[bf][rB * BK3 + sl];
        }
        asm volatile("s_waitcnt lgkmcnt(0)" ::: "memory");  // own reads in regs
        __builtin_amdgcn_sched_barrier(0);
        __builtin_amdgcn_s_barrier();                        // all waves done w/ bf

        // ---- refill this buffer with tile kt+2 (NOT waited here) ----
        if (kt + 2 < NSTEP) STAGE(kt + 2, bf);

        // ---- 16 MFMA on registers (overlaps in-flight loads) ----
        #pragma unroll
        for (int i = 0; i < 4; i++)
            #pragma unroll
            for (int j = 0; j < 2; j++) {
                aC[i][j] = __builtin_amdgcn_mfma_f32_16x16x32_f16(ar[i],  bc[j],  aC[i][j], 0, 0, 0);
                aS[i][j] = __builtin_amdgcn_mfma_f32_16x16x32_f16(ai_[i], bs_[j], aS[i][j], 0, 0, 0);
            }

        // ---- counted wait: tile kt+1 landed, tile kt+2 still in flight ----
        if (kt + 2 < NSTEP) {
            asm volatile("s_waitcnt vmcnt(6)" ::: "memory");
        } else if (kt + 1 < NSTEP) {
            asm volatile("s_waitcnt vmcnt(0)" ::: "memory");
        }
        __builtin_amdgcn_sched_barrier(0);
        __builtin_amdgcn_s_barrier();                        // next buf ready
    }
    #undef STAGE

    // Epilogue (verified R2-R4). C/D layout: col = lane&15 (-> n), row = quad*4 + reg.
    // x[n] = C+S+t (win[n]);  x[1024-n] = C-S+t (win[1024-n]), t = (-1)^n re512/1024.
    #pragma unroll
    for (int j = 0; j < 2; j++) {
        const int n = n0 + wn*32 + j*16 + row16;           // 0..511
        const float wpos = window[n];
        const float wneg = window[(NFFT - n) & (NFFT - 1)]; // n=0 unused
        #pragma unroll
        for (int i = 0; i < 4; i++) {
            const int mrow = m0 + wm*64 + i*16 + quad*4;
            const float4 r5v = *(const float4*)&re512f[mrow];
            const float r5a[4] = {r5v.x, r5v.y, r5v.z, r5v.w};
            const f32x4 c = aC[i][j];
            const f32x4 s = aS[i][j];
            #pragma unroll
            for (int r = 0; r < 4; r++) {
                const float t = (n & 1) ? -r5a[r] : r5a[r];
                const size_t mbase = (size_t)(mrow + r) * NFFT;
                frames[mbase + n] = (_Float16)((c[r] + s[r] + t) * wpos);
                if (n) frames[mbase + NFFT - n] = (_Float16)((c[r] - s[r] + t) * wneg);
            }
        }
    }
}

// ---------------- deterministic overlap-add gather (verified) ----------------
#define OLA_G 64096   // OUT_LEN/8
__global__ __launch_bounds__(256) void ola_gather(const _Float16* __restrict__ frames,
                                                  float* __restrict__ out)
{
    const int idx = blockIdx.x * 256 + threadIdx.x;   // b*OLA_G + r, exact grid
    const int b = idx / OLA_G;
    const int r = idx - b * OLA_G;
    const int s0 = r << 3;
    int tlo = (s0 - 768) >> 8;  if (tlo < 0) tlo = 0;
    int thi = s0 >> 8;          if (thi > TFRAMES-1) thi = TFRAMES-1;
    float sum[8] = {};
    for (int t = tlo; t <= thi; ++t) {
        const f16x8 f = *(const f16x8*)&frames[((size_t)b * TFRAMES + t) * NFFT + (s0 - (t << 8))];
        #pragma unroll
        for (int i = 0; i < 8; i++) sum[i] += (float)f[i];
    }
    f32x4* o = (f32x4*)(out + (size_t)b * OUT_LEN + s0);
    o[0] = (f32x4){sum[0], sum[1], sum[2], sum[3]};
    o[1] = (f32x4){sum[4], sum[5], sum[6], sum[7]};
}

// ---------------- legacy pack kernels (fallback atomic path) ----------------
__global__ __launch_bounds__(256) void pack_A(const float* __restrict__ sre,
                                              const float* __restrict__ sim,
                                              uint4* __restrict__ Au)
{
    const int idx = blockIdx.x * 256 + threadIdx.x;
    const int m = idx >> 7;
    const int j = idx & 127;
    const int k0 = j * 4;
    const size_t base = (size_t)m * BINS + k0;
    union { _Float16 h[8]; uint4 u; } pk;
    if (j == 0) {
        const float re0   = sre[(size_t)m * BINS];
        const float re512 = sre[(size_t)m * BINS + 512];
        pk.h[0] = (_Float16)(re0   * (1.0f/1024.0f));
        pk.h[1] = (_Float16)(re512 * (1.0f/1024.0f));
        #pragma unroll
        for (int i = 1; i < 4; i++) {
            pk.h[2*i]   = (_Float16)( sre[base + i] * (1.0f/512.0f));
            pk.h[2*i+1] = (_Float16)(-sim[base + i] * (1.0f/512.0f));
        }
    } else {
        #pragma unroll
        for (int i = 0; i < 4; i++) {
            pk.h[2*i]   = (_Float16)( sre[base + i] * (1.0f/512.0f));
            pk.h[2*i+1] = (_Float16)(-sim[base + i] * (1.0f/512.0f));
        }
    }
    Au[idx] = pk.u;
}

__global__ __launch_bounds__(256) void pack_B(const float* __restrict__ dcos,
                                              const float* __restrict__ dsin,
                                              unsigned* __restrict__ Bu)
{
    const int idx = blockIdx.x * 256 + threadIdx.x;
    const int n = idx >> 9;
    const int p = idx & 511;
    float b0, b1;
    if (p == 0) {
        b0 = 1.0f;
        b1 = (n & 1) ? -1.0f : 1.0f;
    } else {
        const size_t base = (size_t)n * NFFT + p;
        b0 = dcos[base];
        b1 = dsin[base];
    }
    union { _Float16 h[2]; unsigned u; } pk;
    pk.h[0] = (_Float16)b0;
    pk.h[1] = (_Float16)b1;
    Bu[idx] = pk.u;
}

// ---------------- legacy 128x128 MFMA GEMM (atomic fallback) ----------------
#define BM 128
#define BN 128
#define BK 64

__global__ __launch_bounds__(256, 3) void gemm_f16_atomic(const _Float16* __restrict__ A,
                                                          const _Float16* __restrict__ B,
                                                          const float* __restrict__ window,
                                                          float* __restrict__ out)
{
    __shared__ _Float16 As[BM * BK];
    __shared__ _Float16 Bs[BN * BK];

    const int raw = blockIdx.x;
    const int idx = (raw & 7) * 250 + (raw >> 3);
    const int mt = idx >> 3;
    const int nt = idx & 7;
    const int m0 = mt * BM;
    const int n0 = nt * BN;

    const int tid  = threadIdx.x;
    const int w    = tid >> 6;
    const int lane = tid & 63;
    const int wm   = w & 1;
    const int wn   = w >> 1;
    const int row16 = lane & 15;
    const int quad  = lane >> 4;

    const int srow   = lane >> 3;
    const int schunk = (lane & 7) ^ srow;
    const _Float16* gA = A + (size_t)(m0 + w*32 + srow) * KP + schunk * 8;
    const _Float16* gB = B + (size_t)(n0 + w*32 + srow) * KP + schunk * 8;

    f32x4 acc[4][4] = {};

    for (int k0 = 0; k0 < KP; k0 += BK) {
        #pragma unroll
        for (int t = 0; t < 4; t++) {
            async_copy16(gA + (size_t)t*8*KP + k0, As + (w*4 + t) * 512);
            async_copy16(gB + (size_t)t*8*KP + k0, Bs + (w*4 + t) * 512);
        }
        __syncthreads();
        #pragma unroll
        for (int c = 0; c < 2; c++) {
            f16x8 af[4], bf[4];
            #pragma unroll
            for (int i = 0; i < 4; i++) {
                const int rowA = wm*64 + i*16 + row16;
                const int chA  = (c*4 + quad) ^ (row16 & 7);
                af[i] = *(const f16x8*)&As[rowA * BK + chA * 8];
            }
            #pragma unroll
            for (int j = 0; j < 4; j++) {
                const int rowB = wn*64 + j*16 + row16;
                const int chB  = (c*4 + quad) ^ (row16 & 7);
                bf[j] = *(const f16x8*)&Bs[rowB * BK + chB * 8];
            }
            #pragma unroll
            for (int i = 0; i < 4; i++)
                #pragma unroll
                for (int j = 0; j < 4; j++)
                    acc[i][j] = __builtin_amdgcn_mfma_f32_16x16x32_f16(af[i], bf[j], acc[i][j], 0, 0, 0);
        }
        __syncthreads();
    }

    #pragma unroll
    for (int j = 0; j < 4; j++) {
        const int n = n0 + wn*64 + j*16 + row16;
        const float win = window[n];
        #pragma unroll
        for (int i = 0; i < 4; i++) {
            const int mrow = m0 + wm*64 + i*16 + quad*4;
            const f32x4 c = acc[i][j];
            #pragma unroll
            for (int r = 0; r < 4; r++) {
                const int m = mrow + r;
                const int b = m / TFRAMES;
                const int t = m - b * TFRAMES;
                atomicAdd(&out[(size_t)b * OUT_LEN + (size_t)t * STEP + n], c[r] * win);
            }
        }
    }
}

// ---------------- round-1 fp32 fallback (known-correct) ----------------
#define MT 64
#define NT 64
#define KT 16
#define PAD 4
__global__ __launch_bounds__(256) void istft_gemm_ola_f32(
    const float* __restrict__ sre, const float* __restrict__ sim,
    const float* __restrict__ dcos, const float* __restrict__ dsin,
    const float* __restrict__ window, float* __restrict__ out)
{
    __shared__ float As_re[KT][MT + PAD];
    __shared__ float As_im[KT][MT + PAD];
    __shared__ float Bs_c[KT][NT + PAD];
    __shared__ float Bs_s[KT][NT + PAD];
    const int ntile = blockIdx.x & 15;
    const int mtile = blockIdx.x >> 4;
    const int m0 = mtile * MT, n0 = ntile * NT;
    const int tid = threadIdx.x;
    const int tx = tid & 15, ty = tid >> 4;
    const int lcol = tid & 15, lrow = tid >> 4;
    float acc[4][4] = {};
    for (int k0 = 0; k0 < BINS; k0 += KT) {
        const int k = k0 + lcol;
        const bool kvalid = (k < BINS);
        const float w = kvalid ? ((k == 0 || k == 512) ? (1.0f/1024.0f) : (2.0f/1024.0f)) : 0.0f;
        #pragma unroll
        for (int i = 0; i < 4; i++) {
            const int m = m0 + lrow + i*16;
            const size_t base = (size_t)m * BINS + k;
            As_re[lcol][lrow + i*16] = kvalid ?  w * sre[base] : 0.0f;
            As_im[lcol][lrow + i*16] = kvalid ? -w * sim[base] : 0.0f;
        }
        #pragma unroll
        for (int i = 0; i < 4; i++) {
            const int n = n0 + lrow + i*16;
            const size_t base = (size_t)n * NFFT + k;
            Bs_c[lcol][lrow + i*16] = kvalid ? dcos[base] : 0.0f;
            Bs_s[lcol][lrow + i*16] = kvalid ? dsin[base] : 0.0f;
        }
        __syncthreads();
        #pragma unroll
        for (int kk = 0; kk < KT; kk++) {
            const float4 ar = *(const float4*)&As_re[kk][ty*4];
            const float4 ai = *(const float4*)&As_im[kk][ty*4];
            const float4 bc = *(const float4*)&Bs_c[kk][tx*4];
            const float4 bs = *(const float4*)&Bs_s[kk][tx*4];
            const float a_r[4] = {ar.x, ar.y, ar.z, ar.w};
            const float a_i[4] = {ai.x, ai.y, ai.z, ai.w};
            const float b_c[4] = {bc.x, bc.y, bc.z, bc.w};
            const float b_s[4] = {bs.x, bs.y, bs.z, bs.w};
            #pragma unroll
            for (int i = 0; i < 4; i++)
                #pragma unroll
                for (int j = 0; j < 4; j++)
                    acc[i][j] += a_r[i]*b_c[j] + a_i[i]*b_s[j];
        }
        __syncthreads();
    }
    #pragma unroll
    for (int i = 0; i < 4; i++) {
        const int m = m0 + ty*4 + i;
        const int b = m / TFRAMES;
        const int t = m - b * TFRAMES;
        const size_t obase = (size_t)b * OUT_LEN + (size_t)t * STEP;
        #pragma unroll
        for (int j = 0; j < 4; j++) {
            const int n = n0 + tx*4 + j;
            atomicAdd(&out[obase + n], acc[i][j] * window[n]);
        }
    }
}

// ---------------- launch ----------------
extern "C" void kernel_launch(void* const* d_in, const int* in_sizes, int n_in,
                              void* d_out, int out_size, void* d_ws, size_t ws_size,
                              hipStream_t stream) {
    const float* sre    = (const float*)d_in[0];
    const float* sim    = (const float*)d_in[1];
    const float* dcos   = (const float*)d_in[2];
    const float* dsin   = (const float*)d_in[3];
    const float* window = (const float*)d_in[4];
    float* out = (float*)d_out;

    // fast-path workspace layout
    const size_t WS_AR = (size_t)M_TOTAL * KP2 * sizeof(_Float16);    // 32,768,000
    const size_t WS_AI = WS_AR;
    const size_t WS_R5 = (size_t)M_TOTAL * sizeof(float);             //    128,000
    const size_t WS_BC = (size_t)512 * KP2 * sizeof(_Float16);        //    524,288
    const size_t WS_BS = WS_BC;
    const size_t WS_FR = (size_t)M_TOTAL * NFFT * sizeof(_Float16);   // 65,536,000
    const size_t NEED  = WS_AR + WS_AI + WS_R5 + WS_BC + WS_BS + WS_FR;

    // legacy atomic-path workspace
    const size_t WS_A = (size_t)M_TOTAL * KP * sizeof(_Float16);
    const size_t WS_B = (size_t)NFFT    * KP * sizeof(_Float16);

    if (ws_size >= NEED) {
        char* p = (char*)d_ws;
        _Float16* Ar = (_Float16*)p;  p += WS_AR;
        _Float16* Ai = (_Float16*)p;  p += WS_AI;
        float*    r5 = (float*)p;     p += WS_R5;
        _Float16* Bc = (_Float16*)p;  p += WS_BC;
        _Float16* Bs = (_Float16*)p;  p += WS_BS;
        _Float16* fr = (_Float16*)p;

        pack_AB<<<PACKA_BLOCKS + PACKB_BLOCKS, 256, 0, stream>>>(
            sre, sim, dcos, dsin, window,
            (uint4*)Ar, (uint4*)Ai, r5, fr, (uint4*)Bc, (uint4*)Bs);

        const int grid = (M_TOTAL / BM3) * (KP2 / BN3);   // 250 * 8 = 2000
        gemm_dual<<<grid, 256, 0, stream>>>(Ar, Ai, Bc, Bs, r5, window, fr);
        ola_gather<<<(BATCH * OUT_LEN) / 2048, 256, 0, stream>>>(fr, out);
    } else if (ws_size >= WS_A + WS_B) {
        hipMemsetAsync(out, 0, (size_t)out_size * sizeof(float), stream);
        _Float16* Apk = (_Float16*)d_ws;
        _Float16* Bpk = (_Float16*)((char*)d_ws + WS_A);
        pack_A<<<(M_TOTAL * JPACK) / 256, 256, 0, stream>>>(sre, sim, (uint4*)Apk);
        pack_B<<<(NFFT * PAIRS) / 256, 256, 0, stream>>>(dcos, dsin, (unsigned*)Bpk);
        const int grid = (M_TOTAL / BM) * (NFFT / BN);
        gemm_f16_atomic<<<grid, 256, 0, stream>>>(Apk, Bpk, window, out);
    } else {
        hipMemsetAsync(out, 0, (size_t)out_size * sizeof(float), stream);
        const int grid = (M_TOTAL / MT) * (NFFT / NT);
        istft_gemm_ola_f32<<<grid, 256, 0, stream>>>(sre, sim, dcos, dsin, window, out);
    }
}

// Round 7
// 252.498 us; speedup vs baseline: 1.3037x; 1.0177x over previous
//
#include <hip/hip_runtime.h>

#define BATCH 16
#define TFRAMES 2000
#define BINS 513
#define NFFT 1024
#define STEP 256
#define OUT_LEN 512768            // (TFRAMES-1)*STEP + NFFT
#define M_TOTAL (BATCH*TFRAMES)   // 32000

// ---- legacy packed layout (fallback atomic path) ----
#define KP 1024
#define PAIRS 512
#define JPACK 128

// ---- symmetry-split layout (fast path) ----
// C[n] = sum_p Ar[p]*cos(2pi p n/1024), Ar[0]=re0/1024 (B_cos[n][0]=1), Ar[p]=re[p]/512
// S[n] = sum_p Ai[p]*sin(2pi p n/1024), Ai[p]=-im[p]/512, slot 0 dead (B_sin[n][0]=0)
// x[n]      = C[n]+S[n]+t,  x[1024-n] = C[n]-S[n]+t,  t=(-1)^n*re512/1024, n=0..511
// x[512]    = sum_k (-1)^k Ar[k] + re512/1024   (fused into pack wave-reduce)
#define KP2 512

typedef _Float16 f16x8 __attribute__((ext_vector_type(8)));
typedef float    f32x4 __attribute__((ext_vector_type(4)));

__device__ __forceinline__ void async_copy16(const void* g, void* l) {
    __builtin_amdgcn_global_load_lds(
        (const __attribute__((address_space(1))) unsigned*)g,
        (__attribute__((address_space(3))) unsigned*)l, 16, 0, 0);
}

// ---------------- fused fast-path pack kernel (A + B in one launch) ---------
#define PACKA_BLOCKS ((M_TOTAL * 64) / 256)   // 8000
#define PACKB_BLOCKS ((512 * 64) / 256)       // 128

__global__ __launch_bounds__(256) void pack_AB(const float* __restrict__ sre,
                                               const float* __restrict__ sim,
                                               const float* __restrict__ dcos,
                                               const float* __restrict__ dsin,
                                               const float* __restrict__ window,
                                               uint4* __restrict__ Ar,
                                               uint4* __restrict__ Ai,
                                               float* __restrict__ re512f,
                                               _Float16* __restrict__ frames,
                                               uint4* __restrict__ Bc,
                                               uint4* __restrict__ Bs)
{
    if (blockIdx.x < PACKA_BLOCKS) {
        // ---- A part: one wave per row m; thread j handles k = 8j..8j+7 ----
        const int idx = blockIdx.x * 256 + threadIdx.x;   // m*64 + j
        const int m = idx >> 6;
        const int j = idx & 63;
        const int k0 = j * 8;
        const size_t base = (size_t)m * BINS + k0;
        float ar[8], ai[8];
        #pragma unroll
        for (int i = 0; i < 8; i++) {
            ar[i] =  sre[base + i] * (1.0f/512.0f);
            ai[i] = -sim[base + i] * (1.0f/512.0f);
        }
        float r5 = 0.0f;
        if (j == 0) {
            ar[0] = sre[(size_t)m * BINS] * (1.0f/1024.0f);   // DC, B_cos[n][0]=1
            ai[0] = 0.0f;                                      // dead, B_sin[n][0]=0
            r5 = sre[(size_t)m * BINS + 512] * (1.0f/1024.0f);
            re512f[m] = r5;
        }
        union { _Float16 h[8]; uint4 u; } pr, pi;
        #pragma unroll
        for (int i = 0; i < 8; i++) { pr.h[i] = (_Float16)ar[i]; pi.h[i] = (_Float16)ai[i]; }
        Ar[idx] = pr.u;
        Ai[idx] = pi.u;

        // fused n=512 column: x[512] = sum_k (-1)^k Ar[k] + re512/1024
        float s = ar[0]-ar[1]+ar[2]-ar[3]+ar[4]-ar[5]+ar[6]-ar[7];
        #pragma unroll
        for (int off = 32; off > 0; off >>= 1) s += __shfl_xor(s, off);
        if (j == 0)
            frames[(size_t)m * NFFT + 512] = (_Float16)((s + r5) * window[512]);
    } else {
        // ---- B part ----
        const int idx = (blockIdx.x - PACKA_BLOCKS) * 256 + threadIdx.x;  // n*64 + j
        const int n = idx >> 6;
        const int j = idx & 63;
        const int k0 = j * 8;
        const size_t base = (size_t)n * NFFT + k0;
        union { _Float16 h[8]; uint4 u; } pc, ps;
        #pragma unroll
        for (int i = 0; i < 8; i++) {
            pc.h[i] = (_Float16)dcos[base + i];
            ps.h[i] = (_Float16)dsin[base + i];
        }
        if (j == 0) { pc.h[0] = (_Float16)1.0f; ps.h[0] = (_Float16)0.0f; }
        Bc[idx] = pc.u;
        Bs[idx] = ps.u;
    }
}

// ---------------- dual symmetry GEMM, 128x128 tile, BK=64, 8 K-steps --------
// R3's VERIFIED structure (single-buffered, 2 barriers/step, planar LDS tiles,
// 64-halves rows = 8 x 16B chunks, swizzle slot = chunk^(row&7) applied to the
// per-lane GLOBAL source -> 0 bank conflicts measured) with BN doubled to 128:
// stages 64 KB per step for 256 MFMA (43.7 FLOP/B, 2x R3's intensity).
// Grid 1000 blocks, 2 blocks/CU (64 KB LDS), wave owns a 64x64 dual quadrant.
#define BM3 128
#define BN3 128
#define BK3 64    // halves per matrix per step -> 8 steps over KP2=512

__global__ __launch_bounds__(256, 2) void gemm_dual(
    const _Float16* __restrict__ Ar, const _Float16* __restrict__ Ai,
    const _Float16* __restrict__ Bc, const _Float16* __restrict__ Bs,
    const float* __restrict__ re512f, const float* __restrict__ window,
    _Float16* __restrict__ frames)
{
    __shared__ _Float16 LAr[BM3 * BK3];   // 16 KB
    __shared__ _Float16 LAi[BM3 * BK3];   // 16 KB
    __shared__ _Float16 LBc[BN3 * BK3];   // 16 KB
    __shared__ _Float16 LBs[BN3 * BK3];   // 16 KB

    // XCD-grouping bijection over 1000 = 8 x 125 blocks; the 4 nt-tiles of an
    // mt-slab are consecutive on one XCD (A-slab L2 reuse).
    const int raw = blockIdx.x;                    // 0..999
    const int idx = (raw & 7) * 125 + (raw >> 3);  // bijection
    const int mt = idx >> 2;                       // 0..249
    const int nt = idx & 3;                        // 0..3
    const int m0 = mt * BM3;
    const int n0 = nt * BN3;

    const int tid  = threadIdx.x;
    const int w    = tid >> 6;         // wave 0..3
    const int lane = tid & 63;
    const int wm   = w & 1;            // M-half (64 rows)
    const int wn   = w >> 1;           // N-half (64 cols)
    const int row16 = lane & 15;
    const int quad  = lane >> 4;

    // staging: srow 0..7, swizzled chunk slot (applied to global source);
    // row & 7 == srow for all staged rows (t*8, w*32 are multiples of 8)
    const int srow  = lane >> 3;
    const int sslot = (lane & 7) ^ srow;
    const _Float16* gAr = Ar + (size_t)(m0 + w*32 + srow) * KP2 + sslot * 8;
    const _Float16* gAi = Ai + (size_t)(m0 + w*32 + srow) * KP2 + sslot * 8;
    const _Float16* gBc = Bc + (size_t)(n0 + w*32 + srow) * KP2 + sslot * 8;
    const _Float16* gBs = Bs + (size_t)(n0 + w*32 + srow) * KP2 + sslot * 8;

    f32x4 aC[4][4] = {};
    f32x4 aS[4][4] = {};

    for (int k0 = 0; k0 < KP2; k0 += BK3) {        // 8 steps
        #pragma unroll
        for (int t = 0; t < 4; t++) {
            async_copy16(gAr + (size_t)t*8*KP2 + k0, LAr + (w*32 + t*8) * BK3);
            async_copy16(gAi + (size_t)t*8*KP2 + k0, LAi + (w*32 + t*8) * BK3);
            async_copy16(gBc + (size_t)t*8*KP2 + k0, LBc + (w*32 + t*8) * BK3);
            async_copy16(gBs + (size_t)t*8*KP2 + k0, LBs + (w*32 + t*8) * BK3);
        }
        __syncthreads();               // drain staging

        #pragma unroll
        for (int ks = 0; ks < 2; ks++) {
            f16x8 ar[4], ai_[4], bc[4], bs_[4];
            #pragma unroll
            for (int i = 0; i < 4; i++) {
                const int rA = wm*64 + i*16 + row16;
                const int sl = ((ks*4 + quad) ^ (rA & 7)) * 8;
                ar[i]  = *(const f16x8*)&LAr[rA * BK3 + sl];
                ai_[i] = *(const f16x8*)&LAi[rA * BK3 + sl];
            }
            #pragma unroll
            for (int j = 0; j < 4; j++) {
                const int rB = wn*64 + j*16 + row16;
                const int sl = ((ks*4 + quad) ^ (rB & 7)) * 8;
                bc[j]  = *(const f16x8*)&LBc[rB * BK3 + sl];
                bs_[j] = *(const f16x8*)&LBs[rB * BK3 + sl];
            }
            #pragma unroll
            for (int i = 0; i < 4; i++)
                #pragma unroll
                for (int j = 0; j < 4; j++) {
                    aC[i][j] = __builtin_amdgcn_mfma_f32_16x16x32_f16(ar[i],  bc[j],  aC[i][j], 0, 0, 0);
                    aS[i][j] = __builtin_amdgcn_mfma_f32_16x16x32_f16(ai_[i], bs_[j], aS[i][j], 0, 0, 0);
                }
        }
        __syncthreads();               // all reads retired before overwrite
    }

    // Epilogue (verified R2-R6 math). C/D layout: col = lane&15 (-> n), row = quad*4 + reg.
    // x[n] = C+S+t (win[n]);  x[1024-n] = C-S+t (win[1024-n]), t = (-1)^n re512/1024.
    #pragma unroll
    for (int j = 0; j < 4; j++) {
        const int n = n0 + wn*64 + j*16 + row16;           // 0..511
        const float wpos = window[n];
        const float wneg = window[(NFFT - n) & (NFFT - 1)]; // n=0 unused
        #pragma unroll
        for (int i = 0; i < 4; i++) {
            const int mrow = m0 + wm*64 + i*16 + quad*4;
            const float4 r5v = *(const float4*)&re512f[mrow];
            const float r5a[4] = {r5v.x, r5v.y, r5v.z, r5v.w};
            const f32x4 c = aC[i][j];
            const f32x4 s = aS[i][j];
            #pragma unroll
            for (int r = 0; r < 4; r++) {
                const float t = (n & 1) ? -r5a[r] : r5a[r];
                const size_t mbase = (size_t)(mrow + r) * NFFT;
                frames[mbase + n] = (_Float16)((c[r] + s[r] + t) * wpos);
                if (n) frames[mbase + NFFT - n] = (_Float16)((c[r] - s[r] + t) * wneg);
            }
        }
    }
}

// ---------------- deterministic overlap-add gather (verified) ----------------
#define OLA_G 64096   // OUT_LEN/8
__global__ __launch_bounds__(256) void ola_gather(const _Float16* __restrict__ frames,
                                                  float* __restrict__ out)
{
    const int idx = blockIdx.x * 256 + threadIdx.x;   // b*OLA_G + r, exact grid
    const int b = idx / OLA_G;
    const int r = idx - b * OLA_G;
    const int s0 = r << 3;
    int tlo = (s0 - 768) >> 8;  if (tlo < 0) tlo = 0;
    int thi = s0 >> 8;          if (thi > TFRAMES-1) thi = TFRAMES-1;
    float sum[8] = {};
    for (int t = tlo; t <= thi; ++t) {
        const f16x8 f = *(const f16x8*)&frames[((size_t)b * TFRAMES + t) * NFFT + (s0 - (t << 8))];
        #pragma unroll
        for (int i = 0; i < 8; i++) sum[i] += (float)f[i];
    }
    f32x4* o = (f32x4*)(out + (size_t)b * OUT_LEN + s0);
    o[0] = (f32x4){sum[0], sum[1], sum[2], sum[3]};
    o[1] = (f32x4){sum[4], sum[5], sum[6], sum[7]};
}

// ---------------- legacy pack kernels (fallback atomic path) ----------------
__global__ __launch_bounds__(256) void pack_A(const float* __restrict__ sre,
                                              const float* __restrict__ sim,
                                              uint4* __restrict__ Au)
{
    const int idx = blockIdx.x * 256 + threadIdx.x;
    const int m = idx >> 7;
    const int j = idx & 127;
    const int k0 = j * 4;
    const size_t base = (size_t)m * BINS + k0;
    union { _Float16 h[8]; uint4 u; } pk;
    if (j == 0) {
        const float re0   = sre[(size_t)m * BINS];
        const float re512 = sre[(size_t)m * BINS + 512];
        pk.h[0] = (_Float16)(re0   * (1.0f/1024.0f));
        pk.h[1] = (_Float16)(re512 * (1.0f/1024.0f));
        #pragma unroll
        for (int i = 1; i < 4; i++) {
            pk.h[2*i]   = (_Float16)( sre[base + i] * (1.0f/512.0f));
            pk.h[2*i+1] = (_Float16)(-sim[base + i] * (1.0f/512.0f));
        }
    } else {
        #pragma unroll
        for (int i = 0; i < 4; i++) {
            pk.h[2*i]   = (_Float16)( sre[base + i] * (1.0f/512.0f));
            pk.h[2*i+1] = (_Float16)(-sim[base + i] * (1.0f/512.0f));
        }
    }
    Au[idx] = pk.u;
}

__global__ __launch_bounds__(256) void pack_B(const float* __restrict__ dcos,
                                              const float* __restrict__ dsin,
                                              unsigned* __restrict__ Bu)
{
    const int idx = blockIdx.x * 256 + threadIdx.x;
    const int n = idx >> 9;
    const int p = idx & 511;
    float b0, b1;
    if (p == 0) {
        b0 = 1.0f;
        b1 = (n & 1) ? -1.0f : 1.0f;
    } else {
        const size_t base = (size_t)n * NFFT + p;
        b0 = dcos[base];
        b1 = dsin[base];
    }
    union { _Float16 h[2]; unsigned u; } pk;
    pk.h[0] = (_Float16)b0;
    pk.h[1] = (_Float16)b1;
    Bu[idx] = pk.u;
}

// ---------------- legacy 128x128 MFMA GEMM (atomic fallback) ----------------
#define BM 128
#define BN 128
#define BK 64

__global__ __launch_bounds__(256, 3) void gemm_f16_atomic(const _Float16* __restrict__ A,
                                                          const _Float16* __restrict__ B,
                                                          const float* __restrict__ window,
                                                          float* __restrict__ out)
{
    __shared__ _Float16 As[BM * BK];
    __shared__ _Float16 Bs[BN * BK];

    const int raw = blockIdx.x;
    const int idx = (raw & 7) * 250 + (raw >> 3);
    const int mt = idx >> 3;
    const int nt = idx & 7;
    const int m0 = mt * BM;
    const int n0 = nt * BN;

    const int tid  = threadIdx.x;
    const int w    = tid >> 6;
    const int lane = tid & 63;
    const int wm   = w & 1;
    const int wn   = w >> 1;
    const int row16 = lane & 15;
    const int quad  = lane >> 4;

    const int srow   = lane >> 3;
    const int schunk = (lane & 7) ^ srow;
    const _Float16* gA = A + (size_t)(m0 + w*32 + srow) * KP + schunk * 8;
    const _Float16* gB = B + (size_t)(n0 + w*32 + srow) * KP + schunk * 8;

    f32x4 acc[4][4] = {};

    for (int k0 = 0; k0 < KP; k0 += BK) {
        #pragma unroll
        for (int t = 0; t < 4; t++) {
            async_copy16(gA + (size_t)t*8*KP + k0, As + (w*4 + t) * 512);
            async_copy16(gB + (size_t)t*8*KP + k0, Bs + (w*4 + t) * 512);
        }
        __syncthreads();
        #pragma unroll
        for (int c = 0; c < 2; c++) {
            f16x8 af[4], bf[4];
            #pragma unroll
            for (int i = 0; i < 4; i++) {
                const int rowA = wm*64 + i*16 + row16;
                const int chA  = (c*4 + quad) ^ (row16 & 7);
                af[i] = *(const f16x8*)&As[rowA * BK + chA * 8];
            }
            #pragma unroll
            for (int j = 0; j < 4; j++) {
                const int rowB = wn*64 + j*16 + row16;
                const int chB  = (c*4 + quad) ^ (row16 & 7);
                bf[j] = *(const f16x8*)&Bs[rowB * BK + chB * 8];
            }
            #pragma unroll
            for (int i = 0; i < 4; i++)
                #pragma unroll
                for (int j = 0; j < 4; j++)
                    acc[i][j] = __builtin_amdgcn_mfma_f32_16x16x32_f16(af[i], bf[j], acc[i][j], 0, 0, 0);
        }
        __syncthreads();
    }

    #pragma unroll
    for (int j = 0; j < 4; j++) {
        const int n = n0 + wn*64 + j*16 + row16;
        const float win = window[n];
        #pragma unroll
        for (int i = 0; i < 4; i++) {
            const int mrow = m0 + wm*64 + i*16 + quad*4;
            const f32x4 c = acc[i][j];
            #pragma unroll
            for (int r = 0; r < 4; r++) {
                const int m = mrow + r;
                const int b = m / TFRAMES;
                const int t = m - b * TFRAMES;
                atomicAdd(&out[(size_t)b * OUT_LEN + (size_t)t * STEP + n], c[r] * win);
            }
        }
    }
}

// ---------------- round-1 fp32 fallback (known-correct) ----------------
#define MT 64
#define NT 64
#define KT 16
#define PAD 4
__global__ __launch_bounds__(256) void istft_gemm_ola_f32(
    const float* __restrict__ sre, const float* __restrict__ sim,
    const float* __restrict__ dcos, const float* __restrict__ dsin,
    const float* __restrict__ window, float* __restrict__ out)
{
    __shared__ float As_re[KT][MT + PAD];
    __shared__ float As_im[KT][MT + PAD];
    __shared__ float Bs_c[KT][NT + PAD];
    __shared__ float Bs_s[KT][NT + PAD];
    const int ntile = blockIdx.x & 15;
    const int mtile = blockIdx.x >> 4;
    const int m0 = mtile * MT, n0 = ntile * NT;
    const int tid = threadIdx.x;
    const int tx = tid & 15, ty = tid >> 4;
    const int lcol = tid & 15, lrow = tid >> 4;
    float acc[4][4] = {};
    for (int k0 = 0; k0 < BINS; k0 += KT) {
        const int k = k0 + lcol;
        const bool kvalid = (k < BINS);
        const float w = kvalid ? ((k == 0 || k == 512) ? (1.0f/1024.0f) : (2.0f/1024.0f)) : 0.0f;
        #pragma unroll
        for (int i = 0; i < 4; i++) {
            const int m = m0 + lrow + i*16;
            const size_t base = (size_t)m * BINS + k;
            As_re[lcol][lrow + i*16] = kvalid ?  w * sre[base] : 0.0f;
            As_im[lcol][lrow + i*16] = kvalid ? -w * sim[base] : 0.0f;
        }
        #pragma unroll
        for (int i = 0; i < 4; i++) {
            const int n = n0 + lrow + i*16;
            const size_t base = (size_t)n * NFFT + k;
            Bs_c[lcol][lrow + i*16] = kvalid ? dcos[base] : 0.0f;
            Bs_s[lcol][lrow + i*16] = kvalid ? dsin[base] : 0.0f;
        }
        __syncthreads();
        #pragma unroll
        for (int kk = 0; kk < KT; kk++) {
            const float4 ar = *(const float4*)&As_re[kk][ty*4];
            const float4 ai = *(const float4*)&As_im[kk][ty*4];
            const float4 bc = *(const float4*)&Bs_c[kk][tx*4];
            const float4 bs = *(const float4*)&Bs_s[kk][tx*4];
            const float a_r[4] = {ar.x, ar.y, ar.z, ar.w};
            const float a_i[4] = {ai.x, ai.y, ai.z, ai.w};
            const float b_c[4] = {bc.x, bc.y, bc.z, bc.w};
            const float b_s[4] = {bs.x, bs.y, bs.z, bs.w};
            #pragma unroll
            for (int i = 0; i < 4; i++)
                #pragma unroll
                for (int j = 0; j < 4; j++)
                    acc[i][j] += a_r[i]*b_c[j] + a_i[i]*b_s[j];
        }
        __syncthreads();
    }
    #pragma unroll
    for (int i = 0; i < 4; i++) {
        const int m = m0 + ty*4 + i;
        const int b = m / TFRAMES;
        const int t = m - b * TFRAMES;
        const size_t obase = (size_t)b * OUT_LEN + (size_t)t * STEP;
        #pragma unroll
        for (int j = 0; j < 4; j++) {
            const int n = n0 + tx*4 + j;
            atomicAdd(&out[obase + n], acc[i][j] * window[n]);
        }
    }
}

// ---------------- launch ----------------
extern "C" void kernel_launch(void* const* d_in, const int* in_sizes, int n_in,
                              void* d_out, int out_size, void* d_ws, size_t ws_size,
                              hipStream_t stream) {
    const float* sre    = (const float*)d_in[0];
    const float* sim    = (const float*)d_in[1];
    const float* dcos   = (const float*)d_in[2];
    const float* dsin   = (const float*)d_in[3];
    const float* window = (const float*)d_in[4];
    float* out = (float*)d_out;

    // fast-path workspace layout
    const size_t WS_AR = (size_t)M_TOTAL * KP2 * sizeof(_Float16);    // 32,768,000
    const size_t WS_AI = WS_AR;
    const size_t WS_R5 = (size_t)M_TOTAL * sizeof(float);             //    128,000
    const size_t WS_BC = (size_t)512 * KP2 * sizeof(_Float16);        //    524,288
    const size_t WS_BS = WS_BC;
    const size_t WS_FR = (size_t)M_TOTAL * NFFT * sizeof(_Float16);   // 65,536,000
    const size_t NEED  = WS_AR + WS_AI + WS_R5 + WS_BC + WS_BS + WS_FR;

    // legacy atomic-path workspace
    const size_t WS_A = (size_t)M_TOTAL * KP * sizeof(_Float16);
    const size_t WS_B = (size_t)NFFT    * KP * sizeof(_Float16);

    if (ws_size >= NEED) {
        char* p = (char*)d_ws;
        _Float16* Ar = (_Float16*)p;  p += WS_AR;
        _Float16* Ai = (_Float16*)p;  p += WS_AI;
        float*    r5 = (float*)p;     p += WS_R5;
        _Float16* Bc = (_Float16*)p;  p += WS_BC;
        _Float16* Bs = (_Float16*)p;  p += WS_BS;
        _Float16* fr = (_Float16*)p;

        pack_AB<<<PACKA_BLOCKS + PACKB_BLOCKS, 256, 0, stream>>>(
            sre, sim, dcos, dsin, window,
            (uint4*)Ar, (uint4*)Ai, r5, fr, (uint4*)Bc, (uint4*)Bs);

        const int grid = (M_TOTAL / BM3) * (KP2 / BN3);   // 250 * 4 = 1000
        gemm_dual<<<grid, 256, 0, stream>>>(Ar, Ai, Bc, Bs, r5, window, fr);
        ola_gather<<<(BATCH * OUT_LEN) / 2048, 256, 0, stream>>>(fr, out);
    } else if (ws_size >= WS_A + WS_B) {
        hipMemsetAsync(out, 0, (size_t)out_size * sizeof(float), stream);
        _Float16* Apk = (_Float16*)d_ws;
        _Float16* Bpk = (_Float16*)((char*)d_ws + WS_A);
        pack_A<<<(M_TOTAL * JPACK) / 256, 256, 0, stream>>>(sre, sim, (uint4*)Apk);
        pack_B<<<(NFFT * PAIRS) / 256, 256, 0, stream>>>(dcos, dsin, (unsigned*)Bpk);
        const int grid = (M_TOTAL / BM) * (NFFT / BN);
        gemm_f16_atomic<<<grid, 256, 0, stream>>>(Apk, Bpk, window, out);
    } else {
        hipMemsetAsync(out, 0, (size_t)out_size * sizeof(float), stream);
        const int grid = (M_TOTAL / MT) * (NFFT / NT);
        istft_gemm_ola_f32<<<grid, 256, 0, stream>>>(sre, sim, dcos, dsin, window, out);
    }
}

// Round 8
// 222.418 us; speedup vs baseline: 1.4801x; 1.1352x over previous
//
#include <hip/hip_runtime.h>

#define BATCH 16
#define TFRAMES 2000
#define BINS 513
#define NFFT 1024
#define STEP 256
#define OUT_LEN 512768            // (TFRAMES-1)*STEP + NFFT
#define M_TOTAL (BATCH*TFRAMES)   // 32000

typedef _Float16 f16x8 __attribute__((ext_vector_type(8)));
typedef float    f32x4 __attribute__((ext_vector_type(4)));

// ---------------------------------------------------------------------------
// Real 1024-pt inverse DFT per row via 512-pt complex synthesis DFT (radix-8^3).
//
// Math (verified against reference formula with delta test vectors):
//   X[k] = sre + i*sim, k=0..512; reference forces hermitian mirror and its
//   sin(0)/sin(pi n) factors drop im[0], im[512].
//   Z[q]   = (A[q] + i*w_q*B[q]) / 1024,  q=0..511
//            A = X[q] + conj(X[512-q]),  B = X[q] - conj(X[512-q]),
//            w_q = e^{+2pi i q/1024}   (Z[0] = ((re0+re512) + i(re0-re512))/1024)
//   y[m]   = sum_q Z[q] e^{+2pi i q m / 512}
//   x[2m]  = Re y[m],  x[2m+1] = Im y[m],  frames[n] = x[n]*window[n]
//
// 512 = 8*64: q = q' + 64 q0, m = m0 + 8 m'
//   stage1 (per q'=t): U[m0]   = sum_q0 Z[t+64q0] w8^{q0 m0};  U *= W512^{t m0}
//   64 = 8*8: q' = a+8b, m' = c+8d
//   stage2 (per m0,a): V[c]    = sum_b U'[a+8b] w8^{bc};       V *= w64^{ac}
//   stage3 (per m0,c): y[m0+8c+64d] = sum_a V'[a,c] w8^{ad}
// Twiddles from the INPUT idft tables (exact reference values):
//   w_q    = idft_cos[1][q]   + i idft_sin[1][q]
//   W512^j = idft_cos[2][j]   + i idft_sin[2][j]   (j = t*m0 <= 441)
//   w64^j  = idft_cos[16][j]  + i idft_sin[16][j]  (j = a*c  <= 49)
// ---------------------------------------------------------------------------

__device__ __forceinline__ void dft8(float* xr, float* xi) {
    // in-place 8-pt synthesis DFT: out[m] = sum_q in[q] e^{+2pi i q m/8}
    const float R = 0.70710678118654752f;
    float e0r = xr[0]+xr[4], e0i = xi[0]+xi[4];
    float e1r = xr[0]-xr[4], e1i = xi[0]-xi[4];
    float e2r = xr[2]+xr[6], e2i = xi[2]+xi[6];
    float e3r = xr[2]-xr[6], e3i = xi[2]-xi[6];
    float E0r = e0r+e2r, E0i = e0i+e2i;
    float E2r = e0r-e2r, E2i = e0i-e2i;
    float E1r = e1r-e3i, E1i = e1i+e3r;   // e1 + i e3
    float E3r = e1r+e3i, E3i = e1i-e3r;   // e1 - i e3
    float o0r = xr[1]+xr[5], o0i = xi[1]+xi[5];
    float o1r = xr[1]-xr[5], o1i = xi[1]-xi[5];
    float o2r = xr[3]+xr[7], o2i = xi[3]+xi[7];
    float o3r = xr[3]-xr[7], o3i = xi[3]-xi[7];
    float O0r = o0r+o2r, O0i = o0i+o2i;
    float O2r = o0r-o2r, O2i = o0i-o2i;
    float O1r = o1r-o3i, O1i = o1i+o3r;
    float O3r = o1r+o3i, O3i = o1i-o3r;
    // w8^m * O[m]:  w0=1, w1=R(1+i), w2=i, w3=R(-1+i)
    float T0r = O0r,            T0i = O0i;
    float T1r = R*(O1r-O1i),    T1i = R*(O1r+O1i);
    float T2r = -O2i,           T2i = O2r;
    float T3r = R*(-O3r-O3i),   T3i = R*(O3r-O3i);
    xr[0] = E0r+T0r; xi[0] = E0i+T0i;
    xr[4] = E0r-T0r; xi[4] = E0i-T0i;
    xr[1] = E1r+T1r; xi[1] = E1i+T1i;
    xr[5] = E1r-T1r; xi[5] = E1i-T1i;
    xr[2] = E2r+T2r; xi[2] = E2i+T2i;
    xr[6] = E2r-T2r; xi[6] = E2i-T2i;
    xr[3] = E3r+T3r; xi[3] = E3i+T3i;
    xr[7] = E3r-T3r; xi[7] = E3i-T3i;
}

#define FFT_ROWS_PER_BLOCK 4
#define LSTR 72   // padded LDS row stride: uniform 2-way bank spread (free)

__global__ __launch_bounds__(256) void fft_rows(const float* __restrict__ sre,
                                                const float* __restrict__ sim,
                                                const float* __restrict__ dcos,
                                                const float* __restrict__ dsin,
                                                const float* __restrict__ window,
                                                _Float16* __restrict__ frames)
{
    __shared__ float SR[FFT_ROWS_PER_BLOCK][8][LSTR];   // 9216 B
    __shared__ float SI[FFT_ROWS_PER_BLOCK][8][LSTR];   // 9216 B

    const int tid = threadIdx.x;
    const int r   = tid >> 6;                 // row slot in block
    const int t   = tid & 63;                 // lane within row
    const int row = blockIdx.x * FFT_ROWS_PER_BLOCK + r;   // 0..31999

    const float* xr = sre + (size_t)row * BINS;
    const float* xi = sim + (size_t)row * BINS;
    const float inv = 1.0f / 1024.0f;

    // ---- build Z[t + 64*q0] and 8-pt DFT over q0 (stage 1) ----
    float zr[8], zi[8];
    #pragma unroll
    for (int q0 = 0; q0 < 8; q0++) {
        const int q = t + 64 * q0;
        float Zr, Zi;
        if (q == 0) {
            const float a = xr[0], b = xr[512];
            Zr = (a + b) * inv;
            Zi = (a - b) * inv;
        } else {
            const float xqr = xr[q],        xqi = xi[q];
            const float xmr = xr[512 - q],  xmi = xi[512 - q];
            const float Ar = xqr + xmr,  Ai = xqi - xmi;
            const float Br = xqr - xmr,  Bi = xqi + xmi;
            const float c = dcos[1024 + q], s = dsin[1024 + q];   // w_q
            Zr = (Ar - s * Br - c * Bi) * inv;
            Zi = (Ai + c * Br - s * Bi) * inv;
        }
        zr[q0] = Zr; zi[q0] = Zi;
    }
    dft8(zr, zi);                              // -> U[m0]

    // twiddle W512^{t*m0} and store to LDS as [m0][q'=t]
    #pragma unroll
    for (int m0 = 1; m0 < 8; m0++) {
        const int j = t * m0;                  // <= 441
        const float c = dcos[2048 + j], s = dsin[2048 + j];
        const float tr = zr[m0] * c - zi[m0] * s;
        zi[m0] = zr[m0] * s + zi[m0] * c;
        zr[m0] = tr;
    }
    #pragma unroll
    for (int m0 = 0; m0 < 8; m0++) { SR[r][m0][t] = zr[m0]; SI[r][m0][t] = zi[m0]; }
    __syncthreads();

    // ---- stage 2: per (m0, a): 8-pt DFT over b, twiddle w64^{ac} ----
    const int m0 = t >> 3;
    const int a  = t & 7;
    float vr[8], vi[8];
    #pragma unroll
    for (int b = 0; b < 8; b++) { vr[b] = SR[r][m0][a + 8*b]; vi[b] = SI[r][m0][a + 8*b]; }
    dft8(vr, vi);                              // -> V[c]
    #pragma unroll
    for (int c = 1; c < 8; c++) {
        const int j = a * c;                   // <= 49
        const float cc = dcos[16*1024 + j], ss = dsin[16*1024 + j];
        const float tr = vr[c] * cc - vi[c] * ss;
        vi[c] = vr[c] * ss + vi[c] * cc;
        vr[c] = tr;
    }
    __syncthreads();                           // all reads done before overwrite
    #pragma unroll
    for (int c = 0; c < 8; c++) { SR[r][m0][c*8 + a] = vr[c]; SI[r][m0][c*8 + a] = vi[c]; }
    __syncthreads();

    // ---- stage 3: per (m0, c): 8-pt DFT over a -> y[m0 + 8c + 64d] ----
    const int c3 = t & 7;
    float wr[8], wi[8];
    #pragma unroll
    for (int a2 = 0; a2 < 8; a2++) { wr[a2] = SR[r][m0][c3*8 + a2]; wi[a2] = SI[r][m0][c3*8 + a2]; }
    dft8(wr, wi);                              // -> y[d]

    // ---- windowed f16 store: x[2m]=Re, x[2m+1]=Im, m = m0+8c+64d ----
    const size_t fbase = (size_t)row * NFFT;
    #pragma unroll
    for (int d = 0; d < 8; d++) {
        const int n = 2 * (m0 + 8*c3 + 64*d);
        const float2 wv = *(const float2*)&window[n];
        union { _Float16 h[2]; unsigned u; } pk;
        pk.h[0] = (_Float16)(wr[d] * wv.x);
        pk.h[1] = (_Float16)(wi[d] * wv.y);
        *(unsigned*)&frames[fbase + n] = pk.u;
    }
}

// ---------------- deterministic overlap-add gather (verified R0-R7) ---------
#define OLA_G 64096   // OUT_LEN/8
__global__ __launch_bounds__(256) void ola_gather(const _Float16* __restrict__ frames,
                                                  float* __restrict__ out)
{
    const int idx = blockIdx.x * 256 + threadIdx.x;   // b*OLA_G + r, exact grid
    const int b = idx / OLA_G;
    const int r = idx - b * OLA_G;
    const int s0 = r << 3;
    int tlo = (s0 - 768) >> 8;  if (tlo < 0) tlo = 0;
    int thi = s0 >> 8;          if (thi > TFRAMES-1) thi = TFRAMES-1;
    float sum[8] = {};
    for (int t = tlo; t <= thi; ++t) {
        const f16x8 f = *(const f16x8*)&frames[((size_t)b * TFRAMES + t) * NFFT + (s0 - (t << 8))];
        #pragma unroll
        for (int i = 0; i < 8; i++) sum[i] += (float)f[i];
    }
    f32x4* o = (f32x4*)(out + (size_t)b * OUT_LEN + s0);
    o[0] = (f32x4){sum[0], sum[1], sum[2], sum[3]};
    o[1] = (f32x4){sum[4], sum[5], sum[6], sum[7]};
}

// ---------------- round-1 fp32 fallback (known-correct, needs no ws) --------
#define MT 64
#define NT 64
#define KT 16
#define PAD 4
__global__ __launch_bounds__(256) void istft_gemm_ola_f32(
    const float* __restrict__ sre, const float* __restrict__ sim,
    const float* __restrict__ dcos, const float* __restrict__ dsin,
    const float* __restrict__ window, float* __restrict__ out)
{
    __shared__ float As_re[KT][MT + PAD];
    __shared__ float As_im[KT][MT + PAD];
    __shared__ float Bs_c[KT][NT + PAD];
    __shared__ float Bs_s[KT][NT + PAD];
    const int ntile = blockIdx.x & 15;
    const int mtile = blockIdx.x >> 4;
    const int m0 = mtile * MT, n0 = ntile * NT;
    const int tid = threadIdx.x;
    const int tx = tid & 15, ty = tid >> 4;
    const int lcol = tid & 15, lrow = tid >> 4;
    float acc[4][4] = {};
    for (int k0 = 0; k0 < BINS; k0 += KT) {
        const int k = k0 + lcol;
        const bool kvalid = (k < BINS);
        const float w = kvalid ? ((k == 0 || k == 512) ? (1.0f/1024.0f) : (2.0f/1024.0f)) : 0.0f;
        #pragma unroll
        for (int i = 0; i < 4; i++) {
            const int m = m0 + lrow + i*16;
            const size_t base = (size_t)m * BINS + k;
            As_re[lcol][lrow + i*16] = kvalid ?  w * sre[base] : 0.0f;
            As_im[lcol][lrow + i*16] = kvalid ? -w * sim[base] : 0.0f;
        }
        #pragma unroll
        for (int i = 0; i < 4; i++) {
            const int n = n0 + lrow + i*16;
            const size_t base = (size_t)n * NFFT + k;
            Bs_c[lcol][lrow + i*16] = kvalid ? dcos[base] : 0.0f;
            Bs_s[lcol][lrow + i*16] = kvalid ? dsin[base] : 0.0f;
        }
        __syncthreads();
        #pragma unroll
        for (int kk = 0; kk < KT; kk++) {
            const float4 ar = *(const float4*)&As_re[kk][ty*4];
            const float4 ai = *(const float4*)&As_im[kk][ty*4];
            const float4 bc = *(const float4*)&Bs_c[kk][tx*4];
            const float4 bs = *(const float4*)&Bs_s[kk][tx*4];
            const float a_r[4] = {ar.x, ar.y, ar.z, ar.w};
            const float a_i[4] = {ai.x, ai.y, ai.z, ai.w};
            const float b_c[4] = {bc.x, bc.y, bc.z, bc.w};
            const float b_s[4] = {bs.x, bs.y, bs.z, bs.w};
            #pragma unroll
            for (int i = 0; i < 4; i++)
                #pragma unroll
                for (int j = 0; j < 4; j++)
                    acc[i][j] += a_r[i]*b_c[j] + a_i[i]*b_s[j];
        }
        __syncthreads();
    }
    #pragma unroll
    for (int i = 0; i < 4; i++) {
        const int m = m0 + ty*4 + i;
        const int b = m / TFRAMES;
        const int t = m - b * TFRAMES;
        const size_t obase = (size_t)b * OUT_LEN + (size_t)t * STEP;
        #pragma unroll
        for (int j = 0; j < 4; j++) {
            const int n = n0 + tx*4 + j;
            atomicAdd(&out[obase + n], acc[i][j] * window[n]);
        }
    }
}

// ---------------- launch ----------------
extern "C" void kernel_launch(void* const* d_in, const int* in_sizes, int n_in,
                              void* d_out, int out_size, void* d_ws, size_t ws_size,
                              hipStream_t stream) {
    const float* sre    = (const float*)d_in[0];
    const float* sim    = (const float*)d_in[1];
    const float* dcos   = (const float*)d_in[2];
    const float* dsin   = (const float*)d_in[3];
    const float* window = (const float*)d_in[4];
    float* out = (float*)d_out;

    const size_t WS_FR = (size_t)M_TOTAL * NFFT * sizeof(_Float16);   // 65,536,000

    if (ws_size >= WS_FR) {
        _Float16* fr = (_Float16*)d_ws;
        fft_rows<<<M_TOTAL / FFT_ROWS_PER_BLOCK, 256, 0, stream>>>(
            sre, sim, dcos, dsin, window, fr);
        ola_gather<<<(BATCH * OUT_LEN) / 2048, 256, 0, stream>>>(fr, out);
    } else {
        hipMemsetAsync(out, 0, (size_t)out_size * sizeof(float), stream);
        const int grid = (M_TOTAL / MT) * (BINS + NT - 1) / NT * 0 + (M_TOTAL / MT) * 16;  // 500*16
        istft_gemm_ola_f32<<<grid, 256, 0, stream>>>(sre, sim, dcos, dsin, window, out);
    }
}

// Round 9
// 214.010 us; speedup vs baseline: 1.5382x; 1.0393x over previous
//
#include <hip/hip_runtime.h>

#define BATCH 16
#define TFRAMES 2000
#define BINS 513
#define NFFT 1024
#define STEP 256
#define OUT_LEN 512768            // (TFRAMES-1)*STEP + NFFT
#define M_TOTAL (BATCH*TFRAMES)   // 32000

typedef _Float16 f16x8 __attribute__((ext_vector_type(8)));
typedef float    f32x4 __attribute__((ext_vector_type(4)));

// ---------------------------------------------------------------------------
// Real 1024-pt inverse DFT per row via 512-pt complex synthesis DFT (radix-8^3).
// R8-verified math (passed, absmax 0.00098):
//   Z[q]   = (A[q] + i*w_q*B[q]) / 1024,  q=0..511
//            A = X[q] + conj(X[512-q]),  B = X[q] - conj(X[512-q]),
//            w_q = e^{+2pi i q/1024};  Z[0] = ((re0+re512) + i(re0-re512))/1024
//   y[m]   = sum_q Z[q] e^{+2pi i q m / 512};  x[2m]=Re y, x[2m+1]=Im y
//   frames[n] = x[n]*window[n]
// Radix-8^3 (q = q'+64q0, m = m0+8m', q'=a+8b, m'=c+8d), twiddles from the
// input idft tables: w_q = row1, W512^j = row2, w64^j = row16.
//
// ROUND 9 change (schedule only, math identical): stage-1 inputs are
// async-staged into LDS via 16 global_load_lds dword copies (no VGPR
// round-trip -> all in flight at once), and X[q] / X[512-q] mirrors are
// read from LDS (stride-1, conflict-free). Each input element is read from
// global exactly once.
// ---------------------------------------------------------------------------

__device__ __forceinline__ void dft8(float* xr, float* xi) {
    // in-place 8-pt synthesis DFT: out[m] = sum_q in[q] e^{+2pi i q m/8}
    const float R = 0.70710678118654752f;
    float e0r = xr[0]+xr[4], e0i = xi[0]+xi[4];
    float e1r = xr[0]-xr[4], e1i = xi[0]-xi[4];
    float e2r = xr[2]+xr[6], e2i = xi[2]+xi[6];
    float e3r = xr[2]-xr[6], e3i = xi[2]-xi[6];
    float E0r = e0r+e2r, E0i = e0i+e2i;
    float E2r = e0r-e2r, E2i = e0i-e2i;
    float E1r = e1r-e3i, E1i = e1i+e3r;   // e1 + i e3
    float E3r = e1r+e3i, E3i = e1i-e3r;   // e1 - i e3
    float o0r = xr[1]+xr[5], o0i = xi[1]+xi[5];
    float o1r = xr[1]-xr[5], o1i = xi[1]-xi[5];
    float o2r = xr[3]+xr[7], o2i = xi[3]+xi[7];
    float o3r = xr[3]-xr[7], o3i = xi[3]-xi[7];
    float O0r = o0r+o2r, O0i = o0i+o2i;
    float O2r = o0r-o2r, O2i = o0i-o2i;
    float O1r = o1r-o3i, O1i = o1i+o3r;
    float O3r = o1r+o3i, O3i = o1i-o3r;
    // w8^m * O[m]:  w0=1, w1=R(1+i), w2=i, w3=R(-1+i)
    float T0r = O0r,            T0i = O0i;
    float T1r = R*(O1r-O1i),    T1i = R*(O1r+O1i);
    float T2r = -O2i,           T2i = O2r;
    float T3r = R*(-O3r-O3i),   T3i = R*(O3r-O3i);
    xr[0] = E0r+T0r; xi[0] = E0i+T0i;
    xr[4] = E0r-T0r; xi[4] = E0i-T0i;
    xr[1] = E1r+T1r; xi[1] = E1i+T1i;
    xr[5] = E1r-T1r; xi[5] = E1i-T1i;
    xr[2] = E2r+T2r; xi[2] = E2i+T2i;
    xr[6] = E2r-T2r; xi[6] = E2i-T2i;
    xr[3] = E3r+T3r; xi[3] = E3i+T3i;
    xr[7] = E3r-T3r; xi[7] = E3i-T3i;
}

__device__ __forceinline__ void async_copy4(const float* g, float* l) {
    __builtin_amdgcn_global_load_lds(
        (const __attribute__((address_space(1))) unsigned*)g,
        (__attribute__((address_space(3))) unsigned*)l, 4, 0, 0);
}

#define FFT_ROWS_PER_BLOCK 4
#define LSTR 72   // stage-layout row stride (8 rows x 72 = 576 floats used)

__global__ __launch_bounds__(256) void fft_rows(const float* __restrict__ sre,
                                                const float* __restrict__ sim,
                                                const float* __restrict__ dcos,
                                                const float* __restrict__ dsin,
                                                const float* __restrict__ window,
                                                _Float16* __restrict__ frames)
{
    // one 576-float buffer per row-slot, dual use:
    //   phase 0: [0..511]  = staged input X re/im
    //   stages : [m0*72+t] = working transform state
    __shared__ float LR[FFT_ROWS_PER_BLOCK][8 * LSTR];   // 9216 B
    __shared__ float LI[FFT_ROWS_PER_BLOCK][8 * LSTR];   // 9216 B

    const int tid = threadIdx.x;
    const int r   = tid >> 6;                 // row slot in block (== wave id)
    const int t   = tid & 63;                 // lane within row
    const int row = blockIdx.x * FFT_ROWS_PER_BLOCK + r;   // 0..31999

    const float* xr = sre + (size_t)row * BINS;
    const float* xi = sim + (size_t)row * BINS;
    const float inv = 1.0f / 1024.0f;

    // ---- async-stage X[0..511] re/im into LDS (16 dword copies, all in flight;
    //      dest = wave-uniform base + lane*4, per global_load_lds rule) ----
    #pragma unroll
    for (int k = 0; k < 8; k++) {
        async_copy4(xr + k*64 + t, &LR[r][k*64 + t]);
        async_copy4(xi + k*64 + t, &LI[r][k*64 + t]);
    }

    // independent scalar loads (issue alongside the async batch)
    const float re0   = xr[0];
    const float re512 = xr[512];
    float wc[8], ws[8];
    #pragma unroll
    for (int q0 = 0; q0 < 8; q0++) {
        const int q = t + 64 * q0;
        wc[q0] = dcos[1024 + q];              // w_q (L2-hot, coalesced)
        ws[q0] = dsin[1024 + q];
    }
    __syncthreads();                          // staging landed (vmcnt drain)

    // ---- stage 1: build Z[t + 64*q0] from LDS, 8-pt DFT over q0 ----
    float zr[8], zi[8];
    #pragma unroll
    for (int q0 = 0; q0 < 8; q0++) {
        const int q = t + 64 * q0;
        float Zr, Zi;
        if (q == 0) {
            Zr = (re0 + re512) * inv;
            Zi = (re0 - re512) * inv;
        } else {
            const float xqr = LR[r][q],        xqi = LI[r][q];
            const float xmr = LR[r][512 - q],  xmi = LI[r][512 - q];
            const float Ar = xqr + xmr,  Ai = xqi - xmi;
            const float Br = xqr - xmr,  Bi = xqi + xmi;
            Zr = (Ar - ws[q0] * Br - wc[q0] * Bi) * inv;
            Zi = (Ai + wc[q0] * Br - ws[q0] * Bi) * inv;
        }
        zr[q0] = Zr; zi[q0] = Zi;
    }
    __syncthreads();                          // all input reads retired
    dft8(zr, zi);                             // -> U[m0]

    // twiddle W512^{t*m0} and store to LDS as [m0][q'=t]
    #pragma unroll
    for (int m0 = 1; m0 < 8; m0++) {
        const int j = t * m0;                 // <= 441
        const float c = dcos[2048 + j], s = dsin[2048 + j];
        const float tr = zr[m0] * c - zi[m0] * s;
        zi[m0] = zr[m0] * s + zi[m0] * c;
        zr[m0] = tr;
    }
    #pragma unroll
    for (int m0 = 0; m0 < 8; m0++) { LR[r][m0*LSTR + t] = zr[m0]; LI[r][m0*LSTR + t] = zi[m0]; }
    __syncthreads();

    // ---- stage 2: per (m0, a): 8-pt DFT over b, twiddle w64^{ac} ----
    const int m0 = t >> 3;
    const int a  = t & 7;
    float vr[8], vi[8];
    #pragma unroll
    for (int b = 0; b < 8; b++) { vr[b] = LR[r][m0*LSTR + a + 8*b]; vi[b] = LI[r][m0*LSTR + a + 8*b]; }
    dft8(vr, vi);                             // -> V[c]
    #pragma unroll
    for (int c = 1; c < 8; c++) {
        const int j = a * c;                  // <= 49
        const float cc = dcos[16*1024 + j], ss = dsin[16*1024 + j];
        const float tr = vr[c] * cc - vi[c] * ss;
        vi[c] = vr[c] * ss + vi[c] * cc;
        vr[c] = tr;
    }
    __syncthreads();                          // all reads done before overwrite
    #pragma unroll
    for (int c = 0; c < 8; c++) { LR[r][m0*LSTR + c*8 + a] = vr[c]; LI[r][m0*LSTR + c*8 + a] = vi[c]; }
    __syncthreads();

    // ---- stage 3: per (m0, c): 8-pt DFT over a -> y[m0 + 8c + 64d] ----
    const int c3 = t & 7;
    float wr[8], wi[8];
    #pragma unroll
    for (int a2 = 0; a2 < 8; a2++) { wr[a2] = LR[r][m0*LSTR + c3*8 + a2]; wi[a2] = LI[r][m0*LSTR + c3*8 + a2]; }
    dft8(wr, wi);                             // -> y[d]

    // ---- windowed f16 store: x[2m]=Re, x[2m+1]=Im, m = m0+8c+64d ----
    const size_t fbase = (size_t)row * NFFT;
    #pragma unroll
    for (int d = 0; d < 8; d++) {
        const int n = 2 * (m0 + 8*c3 + 64*d);
        const float2 wv = *(const float2*)&window[n];
        union { _Float16 h[2]; unsigned u; } pk;
        pk.h[0] = (_Float16)(wr[d] * wv.x);
        pk.h[1] = (_Float16)(wi[d] * wv.y);
        *(unsigned*)&frames[fbase + n] = pk.u;
    }
}

// ---------------- deterministic overlap-add gather (verified R0-R8) ---------
#define OLA_G 64096   // OUT_LEN/8
__global__ __launch_bounds__(256) void ola_gather(const _Float16* __restrict__ frames,
                                                  float* __restrict__ out)
{
    const int idx = blockIdx.x * 256 + threadIdx.x;   // b*OLA_G + r, exact grid
    const int b = idx / OLA_G;
    const int r = idx - b * OLA_G;
    const int s0 = r << 3;
    int tlo = (s0 - 768) >> 8;  if (tlo < 0) tlo = 0;
    int thi = s0 >> 8;          if (thi > TFRAMES-1) thi = TFRAMES-1;
    float sum[8] = {};
    for (int t = tlo; t <= thi; ++t) {
        const f16x8 f = *(const f16x8*)&frames[((size_t)b * TFRAMES + t) * NFFT + (s0 - (t << 8))];
        #pragma unroll
        for (int i = 0; i < 8; i++) sum[i] += (float)f[i];
    }
    f32x4* o = (f32x4*)(out + (size_t)b * OUT_LEN + s0);
    o[0] = (f32x4){sum[0], sum[1], sum[2], sum[3]};
    o[1] = (f32x4){sum[4], sum[5], sum[6], sum[7]};
}

// ---------------- round-1 fp32 fallback (known-correct, needs no ws) --------
#define MT 64
#define NT 64
#define KT 16
#define PAD 4
__global__ __launch_bounds__(256) void istft_gemm_ola_f32(
    const float* __restrict__ sre, const float* __restrict__ sim,
    const float* __restrict__ dcos, const float* __restrict__ dsin,
    const float* __restrict__ window, float* __restrict__ out)
{
    __shared__ float As_re[KT][MT + PAD];
    __shared__ float As_im[KT][MT + PAD];
    __shared__ float Bs_c[KT][NT + PAD];
    __shared__ float Bs_s[KT][NT + PAD];
    const int ntile = blockIdx.x & 15;
    const int mtile = blockIdx.x >> 4;
    const int m0 = mtile * MT, n0 = ntile * NT;
    const int tid = threadIdx.x;
    const int tx = tid & 15, ty = tid >> 4;
    const int lcol = tid & 15, lrow = tid >> 4;
    float acc[4][4] = {};
    for (int k0 = 0; k0 < BINS; k0 += KT) {
        const int k = k0 + lcol;
        const bool kvalid = (k < BINS);
        const float w = kvalid ? ((k == 0 || k == 512) ? (1.0f/1024.0f) : (2.0f/1024.0f)) : 0.0f;
        #pragma unroll
        for (int i = 0; i < 4; i++) {
            const int m = m0 + lrow + i*16;
            const size_t base = (size_t)m * BINS + k;
            As_re[lcol][lrow + i*16] = kvalid ?  w * sre[base] : 0.0f;
            As_im[lcol][lrow + i*16] = kvalid ? -w * sim[base] : 0.0f;
        }
        #pragma unroll
        for (int i = 0; i < 4; i++) {
            const int n = n0 + lrow + i*16;
            const size_t base = (size_t)n * NFFT + k;
            Bs_c[lcol][lrow + i*16] = kvalid ? dcos[base] : 0.0f;
            Bs_s[lcol][lrow + i*16] = kvalid ? dsin[base] : 0.0f;
        }
        __syncthreads();
        #pragma unroll
        for (int kk = 0; kk < KT; kk++) {
            const float4 ar = *(const float4*)&As_re[kk][ty*4];
            const float4 ai = *(const float4*)&As_im[kk][ty*4];
            const float4 bc = *(const float4*)&Bs_c[kk][tx*4];
            const float4 bs = *(const float4*)&Bs_s[kk][tx*4];
            const float a_r[4] = {ar.x, ar.y, ar.z, ar.w};
            const float a_i[4] = {ai.x, ai.y, ai.z, ai.w};
            const float b_c[4] = {bc.x, bc.y, bc.z, bc.w};
            const float b_s[4] = {bs.x, bs.y, bs.z, bs.w};
            #pragma unroll
            for (int i = 0; i < 4; i++)
                #pragma unroll
                for (int j = 0; j < 4; j++)
                    acc[i][j] += a_r[i]*b_c[j] + a_i[i]*b_s[j];
        }
        __syncthreads();
    }
    #pragma unroll
    for (int i = 0; i < 4; i++) {
        const int m = m0 + ty*4 + i;
        const int b = m / TFRAMES;
        const int t = m - b * TFRAMES;
        const size_t obase = (size_t)b * OUT_LEN + (size_t)t * STEP;
        #pragma unroll
        for (int j = 0; j < 4; j++) {
            const int n = n0 + tx*4 + j;
            atomicAdd(&out[obase + n], acc[i][j] * window[n]);
        }
    }
}

// ---------------- launch ----------------
extern "C" void kernel_launch(void* const* d_in, const int* in_sizes, int n_in,
                              void* d_out, int out_size, void* d_ws, size_t ws_size,
                              hipStream_t stream) {
    const float* sre    = (const float*)d_in[0];
    const float* sim    = (const float*)d_in[1];
    const float* dcos   = (const float*)d_in[2];
    const float* dsin   = (const float*)d_in[3];
    const float* window = (const float*)d_in[4];
    float* out = (float*)d_out;

    const size_t WS_FR = (size_t)M_TOTAL * NFFT * sizeof(_Float16);   // 65,536,000

    if (ws_size >= WS_FR) {
        _Float16* fr = (_Float16*)d_ws;
        fft_rows<<<M_TOTAL / FFT_ROWS_PER_BLOCK, 256, 0, stream>>>(
            sre, sim, dcos, dsin, window, fr);
        ola_gather<<<(BATCH * OUT_LEN) / 2048, 256, 0, stream>>>(fr, out);
    } else {
        hipMemsetAsync(out, 0, (size_t)out_size * sizeof(float), stream);
        const int grid = (M_TOTAL / MT) * 16;
        istft_gemm_ola_f32<<<grid, 256, 0, stream>>>(sre, sim, dcos, dsin, window, out);
    }
}

// Round 10
// 199.438 us; speedup vs baseline: 1.6506x; 1.0731x over previous
//
#include <hip/hip_runtime.h>

#define BATCH 16
#define TFRAMES 2000
#define BINS 513
#define NFFT 1024
#define STEP 256
#define OUT_LEN 512768            // (TFRAMES-1)*STEP + NFFT
#define M_TOTAL (BATCH*TFRAMES)   // 32000

typedef _Float16 f16x8 __attribute__((ext_vector_type(8)));
typedef float    f32x4 __attribute__((ext_vector_type(4)));

// ---------------------------------------------------------------------------
// Real 1024-pt inverse DFT per row via 512-pt complex synthesis DFT (radix-8^3).
// R8/R9-verified math (passed, absmax 0.00098):
//   Z[q]   = (A[q] + i*w_q*B[q]) / 1024,  q=0..511
//            A = X[q] + conj(X[512-q]),  B = X[q] - conj(X[512-q]),
//            w_q = e^{+2pi i q/1024};  Z[0] = ((re0+re512) + i(re0-re512))/1024
//   y[m]   = sum_q Z[q] e^{+2pi i q m / 512};  x[2m]=Re y, x[2m+1]=Im y
//   frames[n] = x[n]*window[n]
// Radix-8^3 (q = q'+64q0, m = m0+8m', q'=a+8b, m'=c+8d), twiddles from the
// input idft tables: w_q = row1, W512^j = row2, w64^j = row16.
//
// ROUND 10 change (schedule only, math identical): each WAVE processes TWO
// independent rows, interleaved in registers ([2][8] arrays, fully unrolled
// -> compile-time indices). Twiddle gathers are row-invariant: loaded once,
// applied to both rows. Rows-in-flight per CU unchanged (LDS-bound ~32);
// per-wave ILP doubled at every latency point.
// ---------------------------------------------------------------------------

__device__ __forceinline__ void dft8(float* xr, float* xi) {
    // in-place 8-pt synthesis DFT: out[m] = sum_q in[q] e^{+2pi i q m/8}
    const float R = 0.70710678118654752f;
    float e0r = xr[0]+xr[4], e0i = xi[0]+xi[4];
    float e1r = xr[0]-xr[4], e1i = xi[0]-xi[4];
    float e2r = xr[2]+xr[6], e2i = xi[2]+xi[6];
    float e3r = xr[2]-xr[6], e3i = xi[2]-xi[6];
    float E0r = e0r+e2r, E0i = e0i+e2i;
    float E2r = e0r-e2r, E2i = e0i-e2i;
    float E1r = e1r-e3i, E1i = e1i+e3r;   // e1 + i e3
    float E3r = e1r+e3i, E3i = e1i-e3r;   // e1 - i e3
    float o0r = xr[1]+xr[5], o0i = xi[1]+xi[5];
    float o1r = xr[1]-xr[5], o1i = xi[1]-xi[5];
    float o2r = xr[3]+xr[7], o2i = xi[3]+xi[7];
    float o3r = xr[3]-xr[7], o3i = xi[3]-xi[7];
    float O0r = o0r+o2r, O0i = o0i+o2i;
    float O2r = o0r-o2r, O2i = o0i-o2i;
    float O1r = o1r-o3i, O1i = o1i+o3r;
    float O3r = o1r+o3i, O3i = o1i-o3r;
    // w8^m * O[m]:  w0=1, w1=R(1+i), w2=i, w3=R(-1+i)
    float T0r = O0r,            T0i = O0i;
    float T1r = R*(O1r-O1i),    T1i = R*(O1r+O1i);
    float T2r = -O2i,           T2i = O2r;
    float T3r = R*(-O3r-O3i),   T3i = R*(O3r-O3i);
    xr[0] = E0r+T0r; xi[0] = E0i+T0i;
    xr[4] = E0r-T0r; xi[4] = E0i-T0i;
    xr[1] = E1r+T1r; xi[1] = E1i+T1i;
    xr[5] = E1r-T1r; xi[5] = E1i-T1i;
    xr[2] = E2r+T2r; xi[2] = E2i+T2i;
    xr[6] = E2r-T2r; xi[6] = E2i-T2i;
    xr[3] = E3r+T3r; xi[3] = E3i+T3i;
    xr[7] = E3r-T3r; xi[7] = E3i-T3i;
}

__device__ __forceinline__ void async_copy4(const float* g, float* l) {
    __builtin_amdgcn_global_load_lds(
        (const __attribute__((address_space(1))) unsigned*)g,
        (__attribute__((address_space(3))) unsigned*)l, 4, 0, 0);
}

#define ROWS_PER_BLOCK 8          // 4 waves x 2 rows
#define LSTR 72                   // stage-layout row stride (verified R8/R9)

__global__ __launch_bounds__(256, 4) void fft_rows(const float* __restrict__ sre,
                                                   const float* __restrict__ sim,
                                                   const float* __restrict__ dcos,
                                                   const float* __restrict__ dsin,
                                                   const float* __restrict__ window,
                                                   _Float16* __restrict__ frames)
{
    // one 576-float buffer per row-slot, dual use:
    //   phase 0: [0..511]  = staged input X re/im
    //   stages : [m0*72+t] = working transform state
    __shared__ float LR[ROWS_PER_BLOCK][8 * LSTR];   // 18432 B
    __shared__ float LI[ROWS_PER_BLOCK][8 * LSTR];   // 18432 B

    const int tid = threadIdx.x;
    const int wv  = tid >> 6;                 // wave 0..3
    const int t   = tid & 63;                 // lane within wave
    const int r0  = wv * 2;                   // this wave's two row slots
    const int row0 = blockIdx.x * ROWS_PER_BLOCK + r0;   // rows row0, row0+1

    const float* xr[2] = { sre + (size_t)row0 * BINS, sre + (size_t)(row0 + 1) * BINS };
    const float* xi[2] = { sim + (size_t)row0 * BINS, sim + (size_t)(row0 + 1) * BINS };
    const float inv = 1.0f / 1024.0f;

    // ---- async-stage X[0..511] re/im for BOTH rows (32 dword copies in flight;
    //      dest = wave-uniform base + lane*4, per global_load_lds rule) ----
    #pragma unroll
    for (int rr = 0; rr < 2; rr++)
        #pragma unroll
        for (int k = 0; k < 8; k++) {
            async_copy4(xr[rr] + k*64 + t, &LR[r0 + rr][k*64 + t]);
            async_copy4(xi[rr] + k*64 + t, &LI[r0 + rr][k*64 + t]);
        }

    // independent scalar loads (issue alongside the async batch)
    float re0[2], re512[2];
    #pragma unroll
    for (int rr = 0; rr < 2; rr++) { re0[rr] = xr[rr][0]; re512[rr] = xr[rr][512]; }
    float wc[8], ws[8];
    #pragma unroll
    for (int q0 = 0; q0 < 8; q0++) {
        const int q = t + 64 * q0;
        wc[q0] = dcos[1024 + q];              // w_q (row-invariant, L2-hot)
        ws[q0] = dsin[1024 + q];
    }
    __syncthreads();                          // staging landed (vmcnt drain)

    // ---- stage 1: build Z[t + 64*q0] from LDS, 8-pt DFT over q0, both rows --
    float zr[2][8], zi[2][8];
    #pragma unroll
    for (int rr = 0; rr < 2; rr++)
        #pragma unroll
        for (int q0 = 0; q0 < 8; q0++) {
            const int q = t + 64 * q0;
            float Zr, Zi;
            if (q == 0) {
                Zr = (re0[rr] + re512[rr]) * inv;
                Zi = (re0[rr] - re512[rr]) * inv;
            } else {
                const float xqr = LR[r0+rr][q],        xqi = LI[r0+rr][q];
                const float xmr = LR[r0+rr][512 - q],  xmi = LI[r0+rr][512 - q];
                const float Ar = xqr + xmr,  Ai = xqi - xmi;
                const float Br = xqr - xmr,  Bi = xqi + xmi;
                Zr = (Ar - ws[q0] * Br - wc[q0] * Bi) * inv;
                Zi = (Ai + wc[q0] * Br - ws[q0] * Bi) * inv;
            }
            zr[rr][q0] = Zr; zi[rr][q0] = Zi;
        }
    __syncthreads();                          // all input reads retired
    dft8(zr[0], zi[0]);                       // -> U[m0], row 0
    dft8(zr[1], zi[1]);                       // -> U[m0], row 1

    // twiddle W512^{t*m0} (shared) and store to LDS as [m0][q'=t]
    #pragma unroll
    for (int m0 = 1; m0 < 8; m0++) {
        const int j = t * m0;                 // <= 441
        const float c = dcos[2048 + j], s = dsin[2048 + j];
        #pragma unroll
        for (int rr = 0; rr < 2; rr++) {
            const float tr = zr[rr][m0] * c - zi[rr][m0] * s;
            zi[rr][m0] = zr[rr][m0] * s + zi[rr][m0] * c;
            zr[rr][m0] = tr;
        }
    }
    #pragma unroll
    for (int rr = 0; rr < 2; rr++)
        #pragma unroll
        for (int m0 = 0; m0 < 8; m0++) {
            LR[r0+rr][m0*LSTR + t] = zr[rr][m0];
            LI[r0+rr][m0*LSTR + t] = zi[rr][m0];
        }
    __syncthreads();

    // ---- stage 2: per (m0, a): 8-pt DFT over b, twiddle w64^{ac}, both rows -
    const int m0 = t >> 3;
    const int a  = t & 7;
    float vr[2][8], vi[2][8];
    #pragma unroll
    for (int rr = 0; rr < 2; rr++)
        #pragma unroll
        for (int b = 0; b < 8; b++) {
            vr[rr][b] = LR[r0+rr][m0*LSTR + a + 8*b];
            vi[rr][b] = LI[r0+rr][m0*LSTR + a + 8*b];
        }
    dft8(vr[0], vi[0]);                       // -> V[c]
    dft8(vr[1], vi[1]);
    #pragma unroll
    for (int c = 1; c < 8; c++) {
        const int j = a * c;                  // <= 49
        const float cc = dcos[16*1024 + j], ss = dsin[16*1024 + j];
        #pragma unroll
        for (int rr = 0; rr < 2; rr++) {
            const float tr = vr[rr][c] * cc - vi[rr][c] * ss;
            vi[rr][c] = vr[rr][c] * ss + vi[rr][c] * cc;
            vr[rr][c] = tr;
        }
    }
    __syncthreads();                          // all reads done before overwrite
    #pragma unroll
    for (int rr = 0; rr < 2; rr++)
        #pragma unroll
        for (int c = 0; c < 8; c++) {
            LR[r0+rr][m0*LSTR + c*8 + a] = vr[rr][c];
            LI[r0+rr][m0*LSTR + c*8 + a] = vi[rr][c];
        }
    __syncthreads();

    // ---- stage 3: per (m0, c): 8-pt DFT over a -> y[m0 + 8c + 64d], both rows
    const int c3 = t & 7;
    float wr[2][8], wi[2][8];
    #pragma unroll
    for (int rr = 0; rr < 2; rr++)
        #pragma unroll
        for (int a2 = 0; a2 < 8; a2++) {
            wr[rr][a2] = LR[r0+rr][m0*LSTR + c3*8 + a2];
            wi[rr][a2] = LI[r0+rr][m0*LSTR + c3*8 + a2];
        }
    dft8(wr[0], wi[0]);                       // -> y[d]
    dft8(wr[1], wi[1]);

    // ---- windowed f16 store: x[2m]=Re, x[2m+1]=Im, m = m0+8c+64d, both rows -
    #pragma unroll
    for (int rr = 0; rr < 2; rr++) {
        const size_t fbase = (size_t)(row0 + rr) * NFFT;
        #pragma unroll
        for (int d = 0; d < 8; d++) {
            const int n = 2 * (m0 + 8*c3 + 64*d);
            const float2 wv = *(const float2*)&window[n];
            union { _Float16 h[2]; unsigned u; } pk;
            pk.h[0] = (_Float16)(wr[rr][d] * wv.x);
            pk.h[1] = (_Float16)(wi[rr][d] * wv.y);
            *(unsigned*)&frames[fbase + n] = pk.u;
        }
    }
}

// ---------------- deterministic overlap-add gather (verified R0-R9) ---------
#define OLA_G 64096   // OUT_LEN/8
__global__ __launch_bounds__(256) void ola_gather(const _Float16* __restrict__ frames,
                                                  float* __restrict__ out)
{
    const int idx = blockIdx.x * 256 + threadIdx.x;   // b*OLA_G + r, exact grid
    const int b = idx / OLA_G;
    const int r = idx - b * OLA_G;
    const int s0 = r << 3;
    int tlo = (s0 - 768) >> 8;  if (tlo < 0) tlo = 0;
    int thi = s0 >> 8;          if (thi > TFRAMES-1) thi = TFRAMES-1;
    float sum[8] = {};
    for (int t = tlo; t <= thi; ++t) {
        const f16x8 f = *(const f16x8*)&frames[((size_t)b * TFRAMES + t) * NFFT + (s0 - (t << 8))];
        #pragma unroll
        for (int i = 0; i < 8; i++) sum[i] += (float)f[i];
    }
    f32x4* o = (f32x4*)(out + (size_t)b * OUT_LEN + s0);
    o[0] = (f32x4){sum[0], sum[1], sum[2], sum[3]};
    o[1] = (f32x4){sum[4], sum[5], sum[6], sum[7]};
}

// ---------------- round-1 fp32 fallback (known-correct, needs no ws) --------
#define MT 64
#define NT 64
#define KT 16
#define PAD 4
__global__ __launch_bounds__(256) void istft_gemm_ola_f32(
    const float* __restrict__ sre, const float* __restrict__ sim,
    const float* __restrict__ dcos, const float* __restrict__ dsin,
    const float* __restrict__ window, float* __restrict__ out)
{
    __shared__ float As_re[KT][MT + PAD];
    __shared__ float As_im[KT][MT + PAD];
    __shared__ float Bs_c[KT][NT + PAD];
    __shared__ float Bs_s[KT][NT + PAD];
    const int ntile = blockIdx.x & 15;
    const int mtile = blockIdx.x >> 4;
    const int m0 = mtile * MT, n0 = ntile * NT;
    const int tid = threadIdx.x;
    const int tx = tid & 15, ty = tid >> 4;
    const int lcol = tid & 15, lrow = tid >> 4;
    float acc[4][4] = {};
    for (int k0 = 0; k0 < BINS; k0 += KT) {
        const int k = k0 + lcol;
        const bool kvalid = (k < BINS);
        const float w = kvalid ? ((k == 0 || k == 512) ? (1.0f/1024.0f) : (2.0f/1024.0f)) : 0.0f;
        #pragma unroll
        for (int i = 0; i < 4; i++) {
            const int m = m0 + lrow + i*16;
            const size_t base = (size_t)m * BINS + k;
            As_re[lcol][lrow + i*16] = kvalid ?  w * sre[base] : 0.0f;
            As_im[lcol][lrow + i*16] = kvalid ? -w * sim[base] : 0.0f;
        }
        #pragma unroll
        for (int i = 0; i < 4; i++) {
            const int n = n0 + lrow + i*16;
            const size_t base = (size_t)n * NFFT + k;
            Bs_c[lcol][lrow + i*16] = kvalid ? dcos[base] : 0.0f;
            Bs_s[lcol][lrow + i*16] = kvalid ? dsin[base] : 0.0f;
        }
        __syncthreads();
        #pragma unroll
        for (int kk = 0; kk < KT; kk++) {
            const float4 ar = *(const float4*)&As_re[kk][ty*4];
            const float4 ai = *(const float4*)&As_im[kk][ty*4];
            const float4 bc = *(const float4*)&Bs_c[kk][tx*4];
            const float4 bs = *(const float4*)&Bs_s[kk][tx*4];
            const float a_r[4] = {ar.x, ar.y, ar.z, ar.w};
            const float a_i[4] = {ai.x, ai.y, ai.z, ai.w};
            const float b_c[4] = {bc.x, bc.y, bc.z, bc.w};
            const float b_s[4] = {bs.x, bs.y, bs.z, bs.w};
            #pragma unroll
            for (int i = 0; i < 4; i++)
                #pragma unroll
                for (int j = 0; j < 4; j++)
                    acc[i][j] += a_r[i]*b_c[j] + a_i[i]*b_s[j];
        }
        __syncthreads();
    }
    #pragma unroll
    for (int i = 0; i < 4; i++) {
        const int m = m0 + ty*4 + i;
        const int b = m / TFRAMES;
        const int t = m - b * TFRAMES;
        const size_t obase = (size_t)b * OUT_LEN + (size_t)t * STEP;
        #pragma unroll
        for (int j = 0; j < 4; j++) {
            const int n = n0 + tx*4 + j;
            atomicAdd(&out[obase + n], acc[i][j] * window[n]);
        }
    }
}

// ---------------- launch ----------------
extern "C" void kernel_launch(void* const* d_in, const int* in_sizes, int n_in,
                              void* d_out, int out_size, void* d_ws, size_t ws_size,
                              hipStream_t stream) {
    const float* sre    = (const float*)d_in[0];
    const float* sim    = (const float*)d_in[1];
    const float* dcos   = (const float*)d_in[2];
    const float* dsin   = (const float*)d_in[3];
    const float* window = (const float*)d_in[4];
    float* out = (float*)d_out;

    const size_t WS_FR = (size_t)M_TOTAL * NFFT * sizeof(_Float16);   // 65,536,000

    if (ws_size >= WS_FR) {
        _Float16* fr = (_Float16*)d_ws;
        fft_rows<<<M_TOTAL / ROWS_PER_BLOCK, 256, 0, stream>>>(
            sre, sim, dcos, dsin, window, fr);
        ola_gather<<<(BATCH * OUT_LEN) / 2048, 256, 0, stream>>>(fr, out);
    } else {
        hipMemsetAsync(out, 0, (size_t)out_size * sizeof(float), stream);
        const int grid = (M_TOTAL / MT) * 16;
        istft_gemm_ola_f32<<<grid, 256, 0, stream>>>(sre, sim, dcos, dsin, window, out);
    }
}